// Round 9
// baseline (29437.668 us; speedup 1.0000x reference)
//
#include <hip/hip_runtime.h>

#define DI __device__ __forceinline__

constexpr int B_  = 64;
constexpr int T_  = 512;
constexpr int E_  = 256;
constexpr int H_  = 512;
constexpr int G_  = 1536;   // 3*H
constexpr int H2_ = 1024;   // 2*H
constexpr int K_  = 31;
constexpr int BT_ = B_ * T_;
constexpr int TC_ = 64;     // time-chunk length
constexpr int NC_ = T_ / TC_;

typedef float        f32x4  __attribute__((ext_vector_type(4)));
typedef short        bf16x8 __attribute__((ext_vector_type(8)));
typedef unsigned int u32x4  __attribute__((ext_vector_type(4)));
typedef unsigned long long ull;

DI float bf2f(unsigned short u) {
    union { unsigned int i; float f; } v; v.i = ((unsigned int)u) << 16; return v.f;
}
DI unsigned short f2bf(float f) {
    union { float f; unsigned int i; } v; v.f = f;
    unsigned int r = v.i + 0x7fffu + ((v.i >> 16) & 1u);
    return (unsigned short)(r >> 16);
}
DI float sigm(float x) { return 1.f / (1.f + __expf(-x)); }
DI float tanh_(float x) {
    x = fminf(15.f, fmaxf(-15.f, x));
    float e = __expf(-2.f * x);
    return (1.f - e) / (1.f + e);
}

#define MFMA16(a, b, c) __builtin_amdgcn_mfma_f32_16x16x32_bf16(a, b, c, 0, 0, 0)

// classifier weight split halves -> bf16, pad rows 31.. with zeros
__global__ __launch_bounds__(256) void cvt_cls(const float* __restrict__ src,
                                               unsigned short* __restrict__ dstf,
                                               unsigned short* __restrict__ dstb) {
    int i = blockIdx.x * 256 + threadIdx.x;          // [0, 32*512)
    if (i >= 32 * H_) return;
    int n = i >> 9, k = i & 511;
    float vf = (n < K_) ? src[n * H2_ + k] : 0.f;
    float vb = (n < K_) ? src[n * H2_ + H_ + k] : 0.f;
    dstf[i] = f2bf(vf);
    dstb[i] = f2bf(vb);
}

// emissions bias pre-fill (makes later += replay-deterministic)
__global__ __launch_bounds__(256) void emis_bias_init(const float* __restrict__ cls_b,
                                                      float* __restrict__ out1) {
    int i = blockIdx.x * 256 + threadIdx.x;
    int stride = gridDim.x * 256;
    for (; i < BT_ * K_; i += stride) {
        int n = i - (i / K_) * K_;
        out1[i] = cls_b[n];
    }
}

// ---------------- shared GEMM tile body (256 threads; tid = local 0..255) ----------------
template <bool OUTF32, bool ACCUM, bool WF32, bool AGATHER>
DI void gemm_tile(unsigned short (*As)[40], unsigned short (*Ws)[40],
                  const unsigned short* A, const float* gsrc, const int* ids, int lda,
                  size_t arow0, const void* W, int ldw, int nrows, int n0,
                  const float* bias, void* Cout, int ldc, size_t crow0,
                  int nout, int ksz, int tid) {
    const int w = tid >> 6, l = tid & 63;
    const int srow = tid >> 2, sc8 = (tid & 3) * 8;
    const int mw = (w >> 1) * 32, nw = (w & 1) * 32;
    const int fl = l & 15, fk = (l >> 4) * 8;
    f32x4 z4 = { 0.f, 0.f, 0.f, 0.f };
    f32x4 acc[2][2];
    acc[0][0] = z4; acc[0][1] = z4; acc[1][0] = z4; acc[1][1] = z4;
    size_t abase;
    if (AGATHER) abase = (size_t)ids[arow0 + srow] * lda;
    else         abase = (arow0 + srow) * (size_t)lda;

    for (int kc = 0; kc < ksz; kc += 32) {
        u32x4 av, wvv;
        if (AGATHER) {
            const float4* ap = (const float4*)(gsrc + abase + kc + sc8);
            float4 a0 = ap[0], a1 = ap[1];
            union { unsigned short s[8]; u32x4 v; } r;
            r.s[0] = f2bf(a0.x); r.s[1] = f2bf(a0.y); r.s[2] = f2bf(a0.z); r.s[3] = f2bf(a0.w);
            r.s[4] = f2bf(a1.x); r.s[5] = f2bf(a1.y); r.s[6] = f2bf(a1.z); r.s[7] = f2bf(a1.w);
            av = r.v;
        } else {
            av = *(const u32x4*)(A + abase + kc + sc8);
        }
        if (WF32) {
            const float4* wp = (const float4*)((const float*)W + (size_t)(n0 + srow) * ldw + kc + sc8);
            float4 w0 = wp[0], w1 = wp[1];
            union { unsigned short s[8]; u32x4 v; } r;
            r.s[0] = f2bf(w0.x); r.s[1] = f2bf(w0.y); r.s[2] = f2bf(w0.z); r.s[3] = f2bf(w0.w);
            r.s[4] = f2bf(w1.x); r.s[5] = f2bf(w1.y); r.s[6] = f2bf(w1.z); r.s[7] = f2bf(w1.w);
            wvv = r.v;
        } else {
            if (n0 + srow < nrows)
                wvv = *(const u32x4*)((const unsigned short*)W + (size_t)(n0 + srow) * ldw + kc + sc8);
            else { u32x4 zz = { 0u, 0u, 0u, 0u }; wvv = zz; }
        }
        __syncthreads();
        *(u32x4*)&As[srow][sc8] = av;
        *(u32x4*)&Ws[srow][sc8] = wvv;
        __syncthreads();
        bf16x8 a0 = *(const bf16x8*)&As[mw + fl][fk];
        bf16x8 a1 = *(const bf16x8*)&As[mw + 16 + fl][fk];
        bf16x8 b0 = *(const bf16x8*)&Ws[nw + fl][fk];
        bf16x8 b1 = *(const bf16x8*)&Ws[nw + 16 + fl][fk];
        acc[0][0] = MFMA16(a0, b0, acc[0][0]);
        acc[0][1] = MFMA16(a0, b1, acc[0][1]);
        acc[1][0] = MFMA16(a1, b0, acc[1][0]);
        acc[1][1] = MFMA16(a1, b1, acc[1][1]);
    }

    #pragma unroll
    for (int mf = 0; mf < 2; ++mf)
        #pragma unroll
        for (int nf = 0; nf < 2; ++nf) {
            int col = n0 + nw + nf * 16 + fl;
            if (col >= nout) continue;
            float bv = bias ? bias[col] : 0.f;
            #pragma unroll
            for (int j = 0; j < 4; ++j) {
                int r = mw + mf * 16 + (l >> 4) * 4 + j;
                size_t crow = crow0 + r;
                float v = acc[mf][nf][j] + bv;
                if (OUTF32) {
                    float* C = (float*)Cout;
                    if (ACCUM) C[crow * ldc + col] += v;
                    else       C[crow * ldc + col] = v;
                } else {
                    ((unsigned short*)Cout)[crow * ldc + col] = f2bf(v);
                }
            }
        }
}

template <bool OUTF32, bool ACCUM, bool WF32, bool AGATHER>
__global__ __launch_bounds__(256) void gemm_k(
        const unsigned short* __restrict__ A, const float* __restrict__ gsrc,
        const int* __restrict__ ids, int lda, int m_base, int astride,
        const void* __restrict__ W, int ldw, int nrows,
        const float* __restrict__ bias,
        void* __restrict__ Cout, int ldc, int c_base, int cstride, int nout, int ksz) {
    __shared__ unsigned short As[64][40];
    __shared__ unsigned short Ws[64][40];
    gemm_tile<OUTF32, ACCUM, WF32, AGATHER>(As, Ws, A, gsrc, ids, lda,
        (size_t)m_base + (size_t)blockIdx.x * astride, W, ldw, nrows,
        blockIdx.y * 64, bias, Cout, ldc,
        (size_t)c_base + (size_t)blockIdx.x * cstride, nout, ksz, threadIdx.x);
}

// ---------------- fused: 2-block-chain GRU scan (blocks 0-15) + next-chunk xp GEMM ----------------
// Chain = (dir, bg): 16 batches, both blocks (uh=0/1) own 256 units each.
// h exchange: tagged u64 (tag=gs | 2 packed bf16), relaxed agent atomics,
// fire-and-forget (NO drain, NO flags). 2-parity hpub; WAR safe: writer at
// s+2 consumed peer h(s+1) => peer finished reading h(s). Tag retry is
// wave-uniform (1-2 u64/thread) -> no divergent reload storms. Stale values
// across graph replays are bitwise-identical (deterministic) -> correct.
// Per step: issue peer loads -> own-half MFMA (covers RT) -> tag check ->
// LDS stage -> sync -> peer-half MFMA -> gates -> tagged stores + LDS write
// -> sync. Chunk boundary: prologue stages full h from prev dispatch.
template <bool AGATHER>
__global__ __launch_bounds__(1024, 1) void fused_scan_gemm(
        int c, int layer,
        const unsigned short* __restrict__ xpc_f, const unsigned short* __restrict__ xpc_b,
        const float* __restrict__ whh_f, const float* __restrict__ whh_b,
        const float* __restrict__ bhh_f, const float* __restrict__ bhh_b,
        ull* __restrict__ hpub,             // [par][dir][64][256] tagged u64
        float* __restrict__ hcar,           // [dir][B][H] f32 chunk-carry
        unsigned short* __restrict__ out_f, unsigned short* __restrict__ out_b,
        int ldo, int mode,
        const unsigned short* __restrict__ gA, const float* __restrict__ gsrc,
        const int* __restrict__ gids, int glda,
        const float* __restrict__ gwf, const float* __restrict__ gwb,
        const float* __restrict__ gbf, const float* __restrict__ gbb,
        unsigned short* __restrict__ xpf_nxt, unsigned short* __restrict__ xpb_nxt,
        int t0f_n, int t0b_n, int do_gemm) {
    __shared__ char smem[40960];
    const int bid = blockIdx.x;
    const int tid = threadIdx.x;

    if (bid >= 16) {                       // ---- GEMM blocks: next chunk's xp (4 quarters) ----
        if (!do_gemm) return;
        const int qid = (bid - 16) * 4 + (tid >> 8);      // [0,512)
        const int ltid = tid & 255;
        unsigned short (*As)[40] = (unsigned short (*)[40])(smem + (size_t)(tid >> 8) * 10240);
        unsigned short (*Ws)[40] = (unsigned short (*)[40])(smem + (size_t)(tid >> 8) * 10240 + 5120);
        #pragma unroll 1
        for (int it = 0; it < 6; ++it) {
            int job = qid + it * 512;      // 512*6 = 3072 = 2*64*24 exact
            int dirj = job & 1;
            int rest = job >> 1;
            int mt = rest & 63;
            int nt = rest >> 6;
            const float* gw = dirj ? gwb : gwf;
            const float* gbias = dirj ? gbb : gbf;
            unsigned short* gout = dirj ? xpb_nxt : xpf_nxt;
            int t0 = dirj ? t0b_n : t0f_n;
            gemm_tile<false, false, true, AGATHER>(As, Ws, gA, gsrc, gids, glda,
                (size_t)t0 + (size_t)mt * T_, gw, glda, G_, nt * 64, gbias,
                (void*)gout, G_, (size_t)mt * TC_, G_, glda, ltid);
        }
        return;
    }

    // ---- scan blocks: bid = dir*8 + bg*2 + uh ----
    const int dir = bid >> 3;
    const int bg  = (bid >> 1) & 3;
    const int uh  = bid & 1;
    const int puh = 1 - uh;
    const int w = tid >> 6, l = tid & 63;
    const int fl = l & 15, q = l >> 4, fko = q * 8;
    const unsigned short* xp = dir ? xpc_b : xpc_f;
    const float* whh = dir ? whh_b : whh_f;
    const float* bhh = dir ? bhh_b : bhh_f;
    unsigned short* outp = dir ? out_b : out_f;
    unsigned short* hs = (unsigned short*)smem;   // [2][16 rows][512 units], swizzled
    const int mg0 = bg * 16;

    // W_hh -> VGPR fragments (f32 source, convert inline), once per launch
    const int u = uh * 256 + w * 16 + fl;         // this lane's unit (N-col)
    bf16x8 wv[3][16];
    #pragma unroll
    for (int g = 0; g < 3; ++g)
        #pragma unroll
        for (int ks = 0; ks < 16; ++ks) {
            const float* wp = whh + (size_t)(g * H_ + u) * H_ + ks * 32 + fko;
            float4 w0 = *(const float4*)wp, w1 = *(const float4*)(wp + 4);
            union { unsigned short s[8]; bf16x8 v; } r;
            r.s[0] = f2bf(w0.x); r.s[1] = f2bf(w0.y); r.s[2] = f2bf(w0.z); r.s[3] = f2bf(w0.w);
            r.s[4] = f2bf(w1.x); r.s[5] = f2bf(w1.y); r.s[6] = f2bf(w1.z); r.s[7] = f2bf(w1.w);
            wv[g][ks] = r.v;
        }

    const float br_ = bhh[u], bz_ = bhh[H_ + u], bn_ = bhh[2 * H_ + u];

    float hp[4];
    if (c > 0) {
        #pragma unroll
        for (int j = 0; j < 4; ++j) hp[j] = hcar[dir * (B_ * H_) + (mg0 + q * 4 + j) * H_ + u];
    } else {
        #pragma unroll
        for (int j = 0; j < 4; ++j) hp[j] = 0.f;
    }

    unsigned short xg[3][4];
    auto ldxp = [&](int tl) {
        #pragma unroll
        for (int j = 0; j < 4; ++j) {
            const unsigned short* xb = xp + ((size_t)((mg0 + q * 4 + j) * TC_ + tl) * G_) + u;
            xg[0][j] = xb[0]; xg[1][j] = xb[H_]; xg[2][j] = xb[2 * H_];
        }
    };
    ldxp(dir ? (TC_ - 1) : 0);

    // prologue: stage full h(s0-1) from prev dispatch (tags guaranteed valid)
    if (c > 0) {
        const int s0 = c * TC_;
        const int row = tid >> 6;                  // [0,16)
        const int p0 = (tid & 63) * 4;             // [0,256) step 4
        const ull* src = hpub + ((size_t)((((s0 - 1) & 1) * 2 + dir) * 64) + mg0 + row) * 256 + p0;
        ull q0 = __hip_atomic_load(src + 0, __ATOMIC_RELAXED, __HIP_MEMORY_SCOPE_AGENT);
        ull q1 = __hip_atomic_load(src + 1, __ATOMIC_RELAXED, __HIP_MEMORY_SCOPE_AGENT);
        ull q2 = __hip_atomic_load(src + 2, __ATOMIC_RELAXED, __HIP_MEMORY_SCOPE_AGENT);
        ull q3 = __hip_atomic_load(src + 3, __ATOMIC_RELAXED, __HIP_MEMORY_SCOPE_AGENT);
        unsigned int byt = (unsigned int)(((s0 - 1) & 1) * 16384 + row * 1024 + p0 * 4);
        byt ^= ((unsigned int)(row & 7)) << 4;
        union { unsigned int uu[4]; u32x4 v; } pk;
        pk.uu[0] = (unsigned int)q0; pk.uu[1] = (unsigned int)q1;
        pk.uu[2] = (unsigned int)q2; pk.uu[3] = (unsigned int)q3;
        *(u32x4*)((char*)hs + byt) = pk.v;
    }
    __syncthreads();

    for (int sl = 0; sl < TC_; ++sl) {
        const int s  = c * TC_ + sl;
        const int gs = layer * T_ + s;
        const int t = dir ? (T_ - 1 - s) : s;
        const int tloc = dir ? (TC_ - 1 - sl) : sl;
        const unsigned int rpar = (unsigned int)(((s - 1) & 1) * 16384);

        f32x4 z4 = { 0.f, 0.f, 0.f, 0.f };
        f32x4 acc[3];
        acc[0] = z4; acc[1] = z4; acc[2] = z4;

        // per-ks MFMA from swizzled LDS row fl
        #define SCAN_KS(kk)  {                                                          \
            unsigned int byt = (unsigned int)(rpar + fl * 1024 + (kk) * 64 + q * 16);   \
            byt ^= ((unsigned int)(fl & 7)) << 4;                                       \
            bf16x8 afr = *(const bf16x8*)((const char*)hs + byt);                       \
            acc[0] = MFMA16(afr, wv[0][kk], acc[0]);                                    \
            acc[1] = MFMA16(afr, wv[1][kk], acc[1]);                                    \
            acc[2] = MFMA16(afr, wv[2][kk], acc[2]); }

        if (s > 0) {
            if (sl > 0) {
                // issue peer loads (in flight during own-half MFMA)
                const int row = tid >> 6;
                const int p0 = puh * 128 + (tid & 63) * 2;
                const ull* src = hpub + ((size_t)((((s - 1) & 1) * 2 + dir) * 64) + mg0 + row) * 256 + p0;
                ull q0 = __hip_atomic_load(src + 0, __ATOMIC_RELAXED, __HIP_MEMORY_SCOPE_AGENT);
                ull q1 = __hip_atomic_load(src + 1, __ATOMIC_RELAXED, __HIP_MEMORY_SCOPE_AGENT);

                // own-half MFMA (8 ks), constant indices per uh branch
                if (uh == 0) { SCAN_KS(0) SCAN_KS(1) SCAN_KS(2) SCAN_KS(3) SCAN_KS(4) SCAN_KS(5) SCAN_KS(6) SCAN_KS(7) }
                else         { SCAN_KS(8) SCAN_KS(9) SCAN_KS(10) SCAN_KS(11) SCAN_KS(12) SCAN_KS(13) SCAN_KS(14) SCAN_KS(15) }

                // tag check (wave-uniform retry)
                const unsigned int want = (unsigned int)(gs - 1);
                bool ok = ((unsigned int)(q0 >> 32) == want) && ((unsigned int)(q1 >> 32) == want);
                while (!__all(ok)) {
                    __builtin_amdgcn_s_sleep(2);
                    q0 = __hip_atomic_load(src + 0, __ATOMIC_RELAXED, __HIP_MEMORY_SCOPE_AGENT);
                    q1 = __hip_atomic_load(src + 1, __ATOMIC_RELAXED, __HIP_MEMORY_SCOPE_AGENT);
                    ok = ((unsigned int)(q0 >> 32) == want) && ((unsigned int)(q1 >> 32) == want);
                }
                // stage peer half -> LDS
                unsigned int byt = (unsigned int)(rpar + row * 1024 + p0 * 4);
                byt ^= ((unsigned int)(row & 7)) << 4;
                union { unsigned int uu[2]; ull v; } pk;
                pk.uu[0] = (unsigned int)q0; pk.uu[1] = (unsigned int)q1;
                *(ull*)((char*)hs + byt) = pk.v;
                __syncthreads();
                // peer-half MFMA (8 ks)
                if (uh == 0) { SCAN_KS(8) SCAN_KS(9) SCAN_KS(10) SCAN_KS(11) SCAN_KS(12) SCAN_KS(13) SCAN_KS(14) SCAN_KS(15) }
                else         { SCAN_KS(0) SCAN_KS(1) SCAN_KS(2) SCAN_KS(3) SCAN_KS(4) SCAN_KS(5) SCAN_KS(6) SCAN_KS(7) }
            } else {
                // chunk start: full h staged by prologue
                SCAN_KS(0) SCAN_KS(1) SCAN_KS(2) SCAN_KS(3) SCAN_KS(4) SCAN_KS(5) SCAN_KS(6) SCAN_KS(7)
                SCAN_KS(8) SCAN_KS(9) SCAN_KS(10) SCAN_KS(11) SCAN_KS(12) SCAN_KS(13) SCAN_KS(14) SCAN_KS(15)
            }
        }
        #undef SCAN_KS

        // gates
        unsigned short hb16s[4];
        #pragma unroll
        for (int j = 0; j < 4; ++j) {
            float xr = bf2f(xg[0][j]);
            float xz = bf2f(xg[1][j]);
            float xn = bf2f(xg[2][j]);
            float r = sigm(xr + acc[0][j] + br_);
            float z = sigm(xz + acc[1][j] + bz_);
            float nn = tanh_(xn + r * (acc[2][j] + bn_));
            float hv = (1.f - z) * nn + z * hp[j];
            hp[j] = hv;
            hb16s[j] = f2bf(hv);
        }

        // fire-and-forget tagged stores (even-fl lanes) + LDS own-half write
        const ull tagw = ((ull)(unsigned int)gs) << 32;
        ull* hw = hpub + (size_t)((s & 1) * 2 + dir) * (64 * 256);
        const unsigned int wpar = (unsigned int)((s & 1) * 16384);
        #pragma unroll
        for (int j = 0; j < 4; ++j) {
            int ml = q * 4 + j;
            unsigned int pv = (unsigned int)(unsigned short)__shfl_xor((int)hb16s[j], 1);
            if ((fl & 1) == 0) {
                unsigned int pk32 = (unsigned int)hb16s[j] | (pv << 16);
                __hip_atomic_store(hw + (size_t)(mg0 + ml) * 256 + (u >> 1), tagw | pk32,
                                   __ATOMIC_RELAXED, __HIP_MEMORY_SCOPE_AGENT);
            }
            unsigned int byt = (unsigned int)(wpar + ml * 1024 + u * 2);
            byt ^= ((unsigned int)(ml & 7)) << 4;
            *(unsigned short*)((char*)hs + byt) = hb16s[j];
        }

        // outp + next-xp prefetch (off critical path)
        #pragma unroll
        for (int j = 0; j < 4; ++j) {
            int mg = mg0 + q * 4 + j;
            size_t row = mode ? (size_t)(mg * TC_ + tloc) : ((size_t)mg * T_ + t);
            outp[row * ldo + u] = hb16s[j];
        }
        if (sl < TC_ - 1) ldxp(dir ? (TC_ - 2 - sl) : (sl + 1));

        __syncthreads();   // own-half LDS writes visible for next step's own-phase
    }

    #pragma unroll
    for (int j = 0; j < 4; ++j) hcar[dir * (B_ * H_) + (mg0 + q * 4 + j) * H_ + u] = hp[j];
}

// ---------------- CRF: one block (one wave) per batch element ----------------
__global__ __launch_bounds__(64) void crf_kernel(const float* __restrict__ em,     // [BT][K]
                                                 const int* __restrict__ labels,
                                                 const float* __restrict__ start,
                                                 const float* __restrict__ endv,
                                                 const float* __restrict__ trans,
                                                 float* __restrict__ partials) {
    __shared__ float tr[32 * 32];
    const int b = blockIdx.x, l = threadIdx.x;
    for (int e2 = l; e2 < 961; e2 += 64) {
        int r = e2 / 31, cc = e2 - r * 31;
        tr[r * 32 + cc] = trans[e2];
    }
    if (l < 32) tr[31 * 32 + l] = 0.f;
    __syncthreads();
    const int* lab = labels + b * T_;
    const float* eb = em + (size_t)b * T_ * K_;

    float part = 0.f, cnt = 0.f;
    for (int t = l; t < T_; t += 64) {
        int lt = lab[t];
        if (lt > -1) {
            cnt += 1.f;
            if (t > 0) part += tr[lab[t - 1] * 32 + lt] + eb[t * K_ + lt];
        }
    }
    #pragma unroll
    for (int o = 32; o; o >>= 1) { part += __shfl_xor(part, o); cnt += __shfl_xor(cnt, o); }
    int lastidx = (int)cnt - 1;
    float num = part + start[lab[0]] + eb[lab[0]] + endv[lab[lastidx]];

    const int jj = l & 31, half = l >> 5;
    const int i0 = half * 16;
    const int ecol = (jj < K_) ? jj : (K_ - 1);
    float a = (jj < K_) ? (start[jj] + eb[jj]) : -3.0e38f;
    for (int t = 1; t < T_; ++t) {
        float tv[16];
        float m = -3.0e38f;
        #pragma unroll
        for (int k = 0; k < 16; ++k) {
            float av = __shfl(a, i0 + k);
            float x = av + tr[(i0 + k) * 32 + jj];
            tv[k] = x;
            m = fmaxf(m, x);
        }
        float ss = 0.f;
        #pragma unroll
        for (int k = 0; k < 16; ++k) ss += __expf(tv[k] - m);
        float m2 = __shfl_xor(m, 32), s2 = __shfl_xor(ss, 32);
        float M = fmaxf(m, m2);
        float S = ss * __expf(m - M) + s2 * __expf(m2 - M);
        float anew = eb[t * K_ + ecol] + M + __logf(S);
        a = ((lab[t] > -1) && (jj < K_)) ? anew : a;
    }
    float v = (jj < K_) ? (a + endv[jj]) : -3.0e38f;
    float m = v;
    #pragma unroll
    for (int o = 32; o; o >>= 1) m = fmaxf(m, __shfl_xor(m, o));
    float ss = (half == 0 && jj < K_) ? __expf(v - m) : 0.f;
    #pragma unroll
    for (int o = 32; o; o >>= 1) ss += __shfl_xor(ss, o);
    if (l == 0) partials[b] = num - (m + __logf(ss));
}

__global__ __launch_bounds__(64) void loss_reduce(const float* __restrict__ partials,
                                                  float* __restrict__ out) {
    float v = partials[threadIdx.x];
    #pragma unroll
    for (int o = 32; o; o >>= 1) v += __shfl_xor(v, o);
    if (threadIdx.x == 0) out[0] = -v;
}

__global__ void sentinel(float* __restrict__ out, float v) { out[0] = -v; }

// ---------------- host ----------------
extern "C" void kernel_launch(void* const* d_in, const int* in_sizes, int n_in,
                              void* d_out, int out_size, void* d_ws, size_t ws_size,
                              hipStream_t stream) {
    const int*   ids      = (const int*)d_in[0];
    const int*   labels   = (const int*)d_in[1];
    const float* emb      = (const float*)d_in[2];
    const float* wih[4]   = { (const float*)d_in[3], (const float*)d_in[7], (const float*)d_in[11], (const float*)d_in[15] };
    const float* whh[4]   = { (const float*)d_in[4], (const float*)d_in[8], (const float*)d_in[12], (const float*)d_in[16] };
    const float* bih[4]   = { (const float*)d_in[5], (const float*)d_in[9], (const float*)d_in[13], (const float*)d_in[17] };
    const float* bhh[4]   = { (const float*)d_in[6], (const float*)d_in[10], (const float*)d_in[14], (const float*)d_in[18] };
    const float* cls_w    = (const float*)d_in[19];
    const float* cls_b    = (const float*)d_in[20];
    const float* c_start  = (const float*)d_in[21];
    const float* c_end    = (const float*)d_in[22];
    const float* c_trans  = (const float*)d_in[23];
    float* out = (float*)d_out;
    float* out1 = out + 1;

    char* p = (char*)d_ws;
    size_t used = 0;
    auto alloc = [&](size_t bytes) -> char* {
        char* r = p;
        size_t a = (bytes + 255) & ~(size_t)255;
        p += a; used += a;
        return r;
    };
    unsigned short* xpF[2]; unsigned short* xpB[2];
    for (int i = 0; i < 2; ++i) {
        xpF[i] = (unsigned short*)alloc((size_t)B_ * TC_ * G_ * 2);   // 12.6MB each
        xpB[i] = (unsigned short*)alloc((size_t)B_ * TC_ * G_ * 2);
    }
    unsigned short* h1   = (unsigned short*)alloc((size_t)BT_ * H2_ * 2);       // 67MB
    unsigned short* gof  = (unsigned short*)alloc((size_t)B_ * TC_ * H_ * 2);   // 4.2MB
    unsigned short* gob  = (unsigned short*)alloc((size_t)B_ * TC_ * H_ * 2);
    unsigned short* clsf  = (unsigned short*)alloc((size_t)32 * H_ * 2);
    unsigned short* clshb = (unsigned short*)alloc((size_t)32 * H_ * 2);
    ull*            hpub  = (ull*)alloc((size_t)2 * 2 * 64 * 256 * 8);          // 512KB tagged
    float*          hcar  = (float*)alloc((size_t)2 * B_ * H_ * 4);             // 256KB
    float*          partials = (float*)alloc((size_t)B_ * 4);

    if (used > ws_size) {
        sentinel<<<dim3(1), dim3(1), 0, stream>>>(out, (float)(ws_size >> 20));
        return;
    }

    cvt_cls<<<dim3((32 * H_ + 255) / 256), dim3(256), 0, stream>>>(cls_w, clsf, clshb);
    emis_bias_init<<<dim3(1024), dim3(256), 0, stream>>>(cls_b, out1);

    for (int layer = 0; layer < 2; ++layer) {
        const float* wf  = wih[layer * 2 + 0];
        const float* wb  = wih[layer * 2 + 1];
        const float* bf_ = bih[layer * 2 + 0];
        const float* bb_ = bih[layer * 2 + 1];
        const float* whf = whh[layer * 2 + 0];
        const float* whb = whh[layer * 2 + 1];
        const float* bhf = bhh[layer * 2 + 0];
        const float* bhb = bhh[layer * 2 + 1];

        // chunk-0 xp GEMMs (standalone, full grid)
        if (layer == 0) {
            gemm_k<false, false, true, true><<<dim3(64, 24), dim3(256), 0, stream>>>(
                nullptr, emb, ids, E_, 0, T_, wf, E_, G_, bf_, (void*)xpF[0], G_, 0, TC_, G_, E_);
            gemm_k<false, false, true, true><<<dim3(64, 24), dim3(256), 0, stream>>>(
                nullptr, emb, ids, E_, T_ - TC_, T_, wb, E_, G_, bb_, (void*)xpB[0], G_, 0, TC_, G_, E_);
        } else {
            gemm_k<false, false, true, false><<<dim3(64, 24), dim3(256), 0, stream>>>(
                h1, nullptr, nullptr, H2_, 0, T_, wf, H2_, G_, bf_, (void*)xpF[0], G_, 0, TC_, G_, H2_);
            gemm_k<false, false, true, false><<<dim3(64, 24), dim3(256), 0, stream>>>(
                h1, nullptr, nullptr, H2_, T_ - TC_, T_, wb, H2_, G_, bb_, (void*)xpB[0], G_, 0, TC_, G_, H2_);
        }

        for (int c = 0; c < NC_; ++c) {
            int dg = (c + 1 < NC_) ? 1 : 0;
            int t0f_n = (c + 1) * TC_;
            int t0b_n = T_ - (c + 2) * TC_;
            if (layer == 0) {
                fused_scan_gemm<true><<<dim3(144), dim3(1024), 0, stream>>>(
                    c, 0, xpF[c & 1], xpB[c & 1], whf, whb, bhf, bhb, hpub, hcar,
                    h1, h1 + H_, H2_, 0,
                    nullptr, emb, ids, E_, wf, wb, bf_, bb_,
                    xpF[(c + 1) & 1], xpB[(c + 1) & 1], t0f_n, t0b_n, dg);
            } else {
                fused_scan_gemm<false><<<dim3(144), dim3(1024), 0, stream>>>(
                    c, 1, xpF[c & 1], xpB[c & 1], whf, whb, bhf, bhb, hpub, hcar,
                    gof, gob, H_, 1,
                    h1, nullptr, nullptr, H2_, wf, wb, bf_, bb_,
                    xpF[(c + 1) & 1], xpB[(c + 1) & 1], t0f_n, t0b_n, dg);
                // emissions for this chunk (+= into out1)
                int t0f = c * TC_;
                int t0b = T_ - (c + 1) * TC_;
                gemm_k<true, true, false, false><<<dim3(64, 1), dim3(256), 0, stream>>>(
                    gof, nullptr, nullptr, H_, 0, TC_, clsf, H_, 32, nullptr,
                    (void*)out1, K_, t0f, T_, K_, H_);
                gemm_k<true, true, false, false><<<dim3(64, 1), dim3(256), 0, stream>>>(
                    gob, nullptr, nullptr, H_, 0, TC_, clshb, H_, 32, nullptr,
                    (void*)out1, K_, t0b, T_, K_, H_);
            }
        }
    }

    crf_kernel<<<dim3(B_), dim3(64), 0, stream>>>(out1, labels, c_start, c_end, c_trans, partials);
    loss_reduce<<<dim3(1), dim3(64), 0, stream>>>(partials, out);
}

// Round 10
// 6388.437 us; speedup vs baseline: 4.6080x; 4.6080x over previous
//
#include <hip/hip_runtime.h>

#define DI __device__ __forceinline__

constexpr int B_  = 64;
constexpr int T_  = 512;
constexpr int E_  = 256;
constexpr int H_  = 512;
constexpr int G_  = 1536;   // 3*H
constexpr int H2_ = 1024;   // 2*H
constexpr int K_  = 31;
constexpr int BT_ = B_ * T_;
constexpr int TC_ = 64;     // time-chunk length
constexpr int NC_ = T_ / TC_;

typedef float        f32x4  __attribute__((ext_vector_type(4)));
typedef short        bf16x8 __attribute__((ext_vector_type(8)));
typedef unsigned int u32x4  __attribute__((ext_vector_type(4)));
typedef unsigned long long ull;

DI float bf2f(unsigned short u) {
    union { unsigned int i; float f; } v; v.i = ((unsigned int)u) << 16; return v.f;
}
DI unsigned short f2bf(float f) {
    union { float f; unsigned int i; } v; v.f = f;
    unsigned int r = v.i + 0x7fffu + ((v.i >> 16) & 1u);
    return (unsigned short)(r >> 16);
}
DI float sigm(float x) { return 1.f / (1.f + __expf(-x)); }
DI float tanh_(float x) {
    x = fminf(15.f, fmaxf(-15.f, x));
    float e = __expf(-2.f * x);
    return (1.f - e) / (1.f + e);
}

#define MFMA16(a, b, c) __builtin_amdgcn_mfma_f32_16x16x32_bf16(a, b, c, 0, 0, 0)

// classifier weight split halves -> bf16, pad rows 31.. with zeros
__global__ __launch_bounds__(256) void cvt_cls(const float* __restrict__ src,
                                               unsigned short* __restrict__ dstf,
                                               unsigned short* __restrict__ dstb) {
    int i = blockIdx.x * 256 + threadIdx.x;          // [0, 32*512)
    if (i >= 32 * H_) return;
    int n = i >> 9, k = i & 511;
    float vf = (n < K_) ? src[n * H2_ + k] : 0.f;
    float vb = (n < K_) ? src[n * H2_ + H_ + k] : 0.f;
    dstf[i] = f2bf(vf);
    dstb[i] = f2bf(vb);
}

// emissions bias pre-fill (makes later += replay-deterministic)
__global__ __launch_bounds__(256) void emis_bias_init(const float* __restrict__ cls_b,
                                                      float* __restrict__ out1) {
    int i = blockIdx.x * 256 + threadIdx.x;
    int stride = gridDim.x * 256;
    for (; i < BT_ * K_; i += stride) {
        int n = i - (i / K_) * K_;
        out1[i] = cls_b[n];
    }
}

// ---------------- shared GEMM tile body (256 threads) ----------------
template <bool OUTF32, bool ACCUM, bool WF32, bool AGATHER>
DI void gemm_tile(unsigned short (*As)[40], unsigned short (*Ws)[40],
                  const unsigned short* A, const float* gsrc, const int* ids, int lda,
                  size_t arow0, const void* W, int ldw, int nrows, int n0,
                  const float* bias, void* Cout, int ldc, size_t crow0,
                  int nout, int ksz, int tid) {
    const int w = tid >> 6, l = tid & 63;
    const int srow = tid >> 2, sc8 = (tid & 3) * 8;
    const int mw = (w >> 1) * 32, nw = (w & 1) * 32;
    const int fl = l & 15, fk = (l >> 4) * 8;
    f32x4 z4 = { 0.f, 0.f, 0.f, 0.f };
    f32x4 acc[2][2];
    acc[0][0] = z4; acc[0][1] = z4; acc[1][0] = z4; acc[1][1] = z4;
    size_t abase;
    if (AGATHER) abase = (size_t)ids[arow0 + srow] * lda;
    else         abase = (arow0 + srow) * (size_t)lda;

    for (int kc = 0; kc < ksz; kc += 32) {
        u32x4 av, wvv;
        if (AGATHER) {
            const float4* ap = (const float4*)(gsrc + abase + kc + sc8);
            float4 a0 = ap[0], a1 = ap[1];
            union { unsigned short s[8]; u32x4 v; } r;
            r.s[0] = f2bf(a0.x); r.s[1] = f2bf(a0.y); r.s[2] = f2bf(a0.z); r.s[3] = f2bf(a0.w);
            r.s[4] = f2bf(a1.x); r.s[5] = f2bf(a1.y); r.s[6] = f2bf(a1.z); r.s[7] = f2bf(a1.w);
            av = r.v;
        } else {
            av = *(const u32x4*)(A + abase + kc + sc8);
        }
        if (WF32) {
            const float4* wp = (const float4*)((const float*)W + (size_t)(n0 + srow) * ldw + kc + sc8);
            float4 w0 = wp[0], w1 = wp[1];
            union { unsigned short s[8]; u32x4 v; } r;
            r.s[0] = f2bf(w0.x); r.s[1] = f2bf(w0.y); r.s[2] = f2bf(w0.z); r.s[3] = f2bf(w0.w);
            r.s[4] = f2bf(w1.x); r.s[5] = f2bf(w1.y); r.s[6] = f2bf(w1.z); r.s[7] = f2bf(w1.w);
            wvv = r.v;
        } else {
            if (n0 + srow < nrows)
                wvv = *(const u32x4*)((const unsigned short*)W + (size_t)(n0 + srow) * ldw + kc + sc8);
            else { u32x4 zz = { 0u, 0u, 0u, 0u }; wvv = zz; }
        }
        __syncthreads();
        *(u32x4*)&As[srow][sc8] = av;
        *(u32x4*)&Ws[srow][sc8] = wvv;
        __syncthreads();
        bf16x8 a0 = *(const bf16x8*)&As[mw + fl][fk];
        bf16x8 a1 = *(const bf16x8*)&As[mw + 16 + fl][fk];
        bf16x8 b0 = *(const bf16x8*)&Ws[nw + fl][fk];
        bf16x8 b1 = *(const bf16x8*)&Ws[nw + 16 + fl][fk];
        acc[0][0] = MFMA16(a0, b0, acc[0][0]);
        acc[0][1] = MFMA16(a0, b1, acc[0][1]);
        acc[1][0] = MFMA16(a1, b0, acc[1][0]);
        acc[1][1] = MFMA16(a1, b1, acc[1][1]);
    }

    #pragma unroll
    for (int mf = 0; mf < 2; ++mf)
        #pragma unroll
        for (int nf = 0; nf < 2; ++nf) {
            int col = n0 + nw + nf * 16 + fl;
            if (col >= nout) continue;
            float bv = bias ? bias[col] : 0.f;
            #pragma unroll
            for (int j = 0; j < 4; ++j) {
                int r = mw + mf * 16 + (l >> 4) * 4 + j;
                size_t crow = crow0 + r;
                float v = acc[mf][nf][j] + bv;
                if (OUTF32) {
                    float* C = (float*)Cout;
                    if (ACCUM) C[crow * ldc + col] += v;
                    else       C[crow * ldc + col] = v;
                } else {
                    ((unsigned short*)Cout)[crow * ldc + col] = f2bf(v);
                }
            }
        }
}

template <bool OUTF32, bool ACCUM, bool WF32, bool AGATHER>
__global__ __launch_bounds__(256) void gemm_k(
        const unsigned short* __restrict__ A, const float* __restrict__ gsrc,
        const int* __restrict__ ids, int lda, int m_base, int astride,
        const void* __restrict__ W, int ldw, int nrows,
        const float* __restrict__ bias,
        void* __restrict__ Cout, int ldc, int c_base, int cstride, int nout, int ksz) {
    __shared__ unsigned short As[64][40];
    __shared__ unsigned short Ws[64][40];
    gemm_tile<OUTF32, ACCUM, WF32, AGATHER>(As, Ws, A, gsrc, ids, lda,
        (size_t)m_base + (size_t)blockIdx.x * astride, W, ldw, nrows,
        blockIdx.y * 64, bias, Cout, ldc,
        (size_t)c_base + (size_t)blockIdx.x * cstride, nout, ksz, threadIdx.x);
}

// ---------------- fused: persistent GRU scan (blocks 0-63) + next-chunk xp GEMM ----------------
// Round-8 structure (proven 4.57ms): per dir 32 blocks = 8 unit-groups x 4
// batch-groups (16 batches). Sync group = 8 blocks (same dir,bg).
// Delta vs r8: h words are tagged u64 (gs<<32 | 2 packed bf16). Consumer
// speculatively issues its 16 data loads BEFORE the flag poll; after the
// (proven, bounded) flag poll passes it validates tags: hit -> RT3 was hidden
// under the poll; miss -> ONE reload, guaranteed fresh (flags imply producers
// drained). No data-hammering retry loop -> no storms. Producer side is
// byte-identical to r8 (stores -> vmcnt(0) drain -> sync -> tid0 flag).
template <bool AGATHER>
__global__ __launch_bounds__(256, 1) void fused_scan_gemm(
        int c, int layer,
        const unsigned short* __restrict__ xpc_f, const unsigned short* __restrict__ xpc_b,
        const float* __restrict__ whh_f, const float* __restrict__ whh_b,
        const float* __restrict__ bhh_f, const float* __restrict__ bhh_b,
        ull* __restrict__ hpub,             // [parity][dir][B][256] tagged u64
        float* __restrict__ hcar,           // [dir][B][H] f32 chunk-carry
        unsigned short* __restrict__ out_f, unsigned short* __restrict__ out_b,
        int ldo, int mode, int* __restrict__ flags,
        const unsigned short* __restrict__ gA, const float* __restrict__ gsrc,
        const int* __restrict__ gids, int glda,
        const float* __restrict__ gwf, const float* __restrict__ gwb,
        const float* __restrict__ gbf, const float* __restrict__ gbb,
        unsigned short* __restrict__ xpf_nxt, unsigned short* __restrict__ xpb_nxt,
        int t0f_n, int t0b_n, int do_gemm) {
    __shared__ unsigned short As[64][40];
    __shared__ unsigned short Ws[64][40];
    __shared__ unsigned short hs[16 * 512];          // 16KB staged h(s-1), swizzled
    const int bid = blockIdx.x;
    const int tid = threadIdx.x;

    if (bid >= 64) {                       // ---- GEMM blocks: next chunk's xp ----
        if (!do_gemm) return;
        const int gb = bid - 64;
        // W-tile-stationary job order: 16 consecutive jobs share one (dir, nt)
        #pragma unroll 1
        for (int it = 0; it < 16; ++it) {
            int job = gb * 16 + it;        // [0, 3072) = 2 dirs * 24 nt * 64 mt
            int dirj = job / 1536;
            int r2 = job - dirj * 1536;
            int nt = r2 >> 6;
            int mt = r2 & 63;
            const float* gw = dirj ? gwb : gwf;
            const float* gbias = dirj ? gbb : gbf;
            unsigned short* gout = dirj ? xpb_nxt : xpf_nxt;
            int t0 = dirj ? t0b_n : t0f_n;
            gemm_tile<false, false, true, AGATHER>(As, Ws, gA, gsrc, gids, glda,
                (size_t)t0 + (size_t)mt * T_, gw, glda, G_, nt * 64, gbias,
                (void*)gout, G_, (size_t)mt * TC_, G_, glda, tid);
        }
        return;
    }

    // ---- scan blocks ----
    const int dir = bid >> 5;
    const int rb  = bid & 31;
    const int ug  = rb >> 2;               // unit-group [0,8)
    const int bg  = rb & 3;                // batch-group [0,4)
    const int w = tid >> 6, l = tid & 63;
    const int fl = l & 15, q = l >> 4, fko = q * 8;
    const unsigned short* xp = dir ? xpc_b : xpc_f;
    const float* whh = dir ? whh_b : whh_f;
    const float* bhh = dir ? bhh_b : bhh_f;
    unsigned short* outp = dir ? out_b : out_f;
    int* pollb  = flags + (dir * 4 + bg) * 8 * 32;   // 8 flags, 128B apart
    int* myflag = pollb + ug * 32;

    // W_hh -> VGPR fragments (f32 source, convert inline), once per chunk
    const int u0w = ug * 64 + w * 16;
    bf16x8 wv[3][16];
    #pragma unroll
    for (int g = 0; g < 3; ++g)
        #pragma unroll
        for (int ks = 0; ks < 16; ++ks) {
            const float* wp = whh + (size_t)(g * H_ + u0w + fl) * H_ + ks * 32 + fko;
            float4 w0 = *(const float4*)wp, w1 = *(const float4*)(wp + 4);
            union { unsigned short s[8]; bf16x8 v; } r;
            r.s[0] = f2bf(w0.x); r.s[1] = f2bf(w0.y); r.s[2] = f2bf(w0.z); r.s[3] = f2bf(w0.w);
            r.s[4] = f2bf(w1.x); r.s[5] = f2bf(w1.y); r.s[6] = f2bf(w1.z); r.s[7] = f2bf(w1.w);
            wv[g][ks] = r.v;
        }

    const int u = u0w + fl;
    const float br_ = bhh[u], bz_ = bhh[H_ + u], bn_ = bhh[2 * H_ + u];
    const int mb = bg * 16 + q * 4;        // epilogue batch base (4 rows)
    const int srowl = tid >> 4;            // stage: local row [0,16)
    const int sseg  = tid & 15;            // stage: 16-u64 segment

    float hp[4];
    if (c > 0) {
        #pragma unroll
        for (int j = 0; j < 4; ++j) hp[j] = hcar[dir * (B_ * H_) + (mb + j) * H_ + u];
    } else {
        #pragma unroll
        for (int j = 0; j < 4; ++j) hp[j] = 0.f;
    }

    unsigned short xg[3][4];
    auto ldxp = [&](int tl) {
        #pragma unroll
        for (int j = 0; j < 4; ++j) {
            const unsigned short* xb = xp + ((size_t)((mb + j) * TC_ + tl) * G_) + u;
            xg[0][j] = xb[0]; xg[1][j] = xb[H_]; xg[2][j] = xb[2 * H_];
        }
    };
    ldxp(dir ? (TC_ - 1) : 0);

    for (int sl = 0; sl < TC_; ++sl) {
        const int s  = c * TC_ + sl;
        const int gs = layer * T_ + s;
        const int t = dir ? (T_ - 1 - s) : s;
        const int tloc = dir ? (TC_ - 1 - sl) : sl;

        f32x4 z4 = { 0.f, 0.f, 0.f, 0.f };
        f32x4 acc[3];
        acc[0] = z4; acc[1] = z4; acc[2] = z4;

        if (s > 0) {
            const ull* src = hpub
                + ((size_t)((((s - 1) & 1) * 2 + dir) * B_) + bg * 16 + srowl) * 256
                + sseg * 16;
            // speculative tagged loads (RT overlapped with flag poll)
            ull qv[16];
            #pragma unroll
            for (int i = 0; i < 16; ++i)
                qv[i] = __hip_atomic_load(src + i, __ATOMIC_RELAXED, __HIP_MEMORY_SCOPE_AGENT);

            if (sl > 0) {                  // chunk start: prev launch done via stream order
                int v = gs;
                if (l < 8) v = __hip_atomic_load(pollb + l * 32, __ATOMIC_RELAXED, __HIP_MEMORY_SCOPE_AGENT);
                while (!__all(v >= gs)) {
                    __builtin_amdgcn_s_sleep(1);
                    if (l < 8) v = __hip_atomic_load(pollb + l * 32, __ATOMIC_RELAXED, __HIP_MEMORY_SCOPE_AGENT);
                }
                asm volatile("" ::: "memory");
            }
            // validate tags; on miss reload once (flags guarantee freshness)
            {
                const unsigned int want = (unsigned int)(gs - 1);
                bool ok = true;
                #pragma unroll
                for (int i = 0; i < 16; ++i) ok = ok && ((unsigned int)(qv[i] >> 32) == want);
                while (!__all(ok)) {
                    #pragma unroll
                    for (int i = 0; i < 16; ++i)
                        qv[i] = __hip_atomic_load(src + i, __ATOMIC_RELAXED, __HIP_MEMORY_SCOPE_AGENT);
                    ok = true;
                    #pragma unroll
                    for (int i = 0; i < 16; ++i) ok = ok && ((unsigned int)(qv[i] >> 32) == want);
                }
            }
            // stage payloads -> LDS (swizzled)
            {
                char* dst = (char*)hs + srowl * 1024;
                #pragma unroll
                for (int i = 0; i < 4; ++i) {
                    unsigned int byt = (unsigned int)(sseg * 64 + i * 16);
                    byt ^= ((unsigned int)(srowl & 7)) << 4;
                    union { unsigned int uu[4]; u32x4 v4; } pk;
                    pk.uu[0] = (unsigned int)qv[4 * i];
                    pk.uu[1] = (unsigned int)qv[4 * i + 1];
                    pk.uu[2] = (unsigned int)qv[4 * i + 2];
                    pk.uu[3] = (unsigned int)qv[4 * i + 3];
                    *(u32x4*)(dst + byt) = pk.v4;
                }
            }
            __syncthreads();
            #pragma unroll
            for (int ks = 0; ks < 16; ++ks) {
                unsigned int byt = (unsigned int)(ks * 64 + q * 16);
                byt ^= ((unsigned int)(fl & 7)) << 4;
                bf16x8 afr = *(const bf16x8*)((const char*)hs + fl * 1024 + byt);
                acc[0] = MFMA16(afr, wv[0][ks], acc[0]);
                acc[1] = MFMA16(afr, wv[1][ks], acc[1]);
                acc[2] = MFMA16(afr, wv[2][ks], acc[2]);
            }
        }

        unsigned short hb16s[4];
        #pragma unroll
        for (int j = 0; j < 4; ++j) {
            float xr = bf2f(xg[0][j]);
            float xz = bf2f(xg[1][j]);
            float xn = bf2f(xg[2][j]);
            float r = sigm(xr + acc[0][j] + br_);
            float z = sigm(xz + acc[1][j] + bz_);
            float nn = tanh_(xn + r * (acc[2][j] + bn_));
            float hv = (1.f - z) * nn + z * hp[j];
            hp[j] = hv;
            hb16s[j] = f2bf(hv);
        }

        // tagged h stores (even-fl lanes), drain, block flag  (r8 protocol)
        const ull tagw = ((ull)(unsigned int)gs) << 32;
        ull* hw = hpub + (size_t)((s & 1) * 2 + dir) * (B_ * 256);
        #pragma unroll
        for (int j = 0; j < 4; ++j) {
            unsigned int pv = (unsigned int)(unsigned short)__shfl_xor((int)hb16s[j], 1);
            if ((fl & 1) == 0) {
                unsigned int pk32 = (unsigned int)hb16s[j] | (pv << 16);
                __hip_atomic_store(hw + (size_t)(mb + j) * 256 + (u >> 1), tagw | pk32,
                                   __ATOMIC_RELAXED, __HIP_MEMORY_SCOPE_AGENT);
            }
        }
        asm volatile("s_waitcnt vmcnt(0)" ::: "memory");
        __syncthreads();                   // all waves' stores acked + LDS reads done
        if (tid == 0)
            __hip_atomic_store(myflag, gs + 1, __ATOMIC_RELAXED, __HIP_MEMORY_SCOPE_AGENT);

        // outp + next-xp prefetch overlap the peers' polling
        #pragma unroll
        for (int j = 0; j < 4; ++j) {
            size_t row = mode ? (size_t)((mb + j) * TC_ + tloc) : ((size_t)(mb + j) * T_ + t);
            outp[row * ldo + u] = hb16s[j];
        }
        if (sl < TC_ - 1) ldxp(dir ? (TC_ - 2 - sl) : (sl + 1));
    }

    #pragma unroll
    for (int j = 0; j < 4; ++j) hcar[dir * (B_ * H_) + (mb + j) * H_ + u] = hp[j];
}

// ---------------- CRF: one block (one wave) per batch element ----------------
__global__ __launch_bounds__(64) void crf_kernel(const float* __restrict__ em,     // [BT][K]
                                                 const int* __restrict__ labels,
                                                 const float* __restrict__ start,
                                                 const float* __restrict__ endv,
                                                 const float* __restrict__ trans,
                                                 float* __restrict__ partials) {
    __shared__ float tr[32 * 32];
    const int b = blockIdx.x, l = threadIdx.x;
    for (int e2 = l; e2 < 961; e2 += 64) {
        int r = e2 / 31, cc = e2 - r * 31;
        tr[r * 32 + cc] = trans[e2];
    }
    if (l < 32) tr[31 * 32 + l] = 0.f;
    __syncthreads();
    const int* lab = labels + b * T_;
    const float* eb = em + (size_t)b * T_ * K_;

    float part = 0.f, cnt = 0.f;
    for (int t = l; t < T_; t += 64) {
        int lt = lab[t];
        if (lt > -1) {
            cnt += 1.f;
            if (t > 0) part += tr[lab[t - 1] * 32 + lt] + eb[t * K_ + lt];
        }
    }
    #pragma unroll
    for (int o = 32; o; o >>= 1) { part += __shfl_xor(part, o); cnt += __shfl_xor(cnt, o); }
    int lastidx = (int)cnt - 1;
    float num = part + start[lab[0]] + eb[lab[0]] + endv[lab[lastidx]];

    const int jj = l & 31, half = l >> 5;
    const int i0 = half * 16;
    const int ecol = (jj < K_) ? jj : (K_ - 1);
    float a = (jj < K_) ? (start[jj] + eb[jj]) : -3.0e38f;
    for (int t = 1; t < T_; ++t) {
        float tv[16];
        float m = -3.0e38f;
        #pragma unroll
        for (int k = 0; k < 16; ++k) {
            float av = __shfl(a, i0 + k);
            float x = av + tr[(i0 + k) * 32 + jj];
            tv[k] = x;
            m = fmaxf(m, x);
        }
        float ss = 0.f;
        #pragma unroll
        for (int k = 0; k < 16; ++k) ss += __expf(tv[k] - m);
        float m2 = __shfl_xor(m, 32), s2 = __shfl_xor(ss, 32);
        float M = fmaxf(m, m2);
        float S = ss * __expf(m - M) + s2 * __expf(m2 - M);
        float anew = eb[t * K_ + ecol] + M + __logf(S);
        a = ((lab[t] > -1) && (jj < K_)) ? anew : a;
    }
    float v = (jj < K_) ? (a + endv[jj]) : -3.0e38f;
    float m = v;
    #pragma unroll
    for (int o = 32; o; o >>= 1) m = fmaxf(m, __shfl_xor(m, o));
    float ss = (half == 0 && jj < K_) ? __expf(v - m) : 0.f;
    #pragma unroll
    for (int o = 32; o; o >>= 1) ss += __shfl_xor(ss, o);
    if (l == 0) partials[b] = num - (m + __logf(ss));
}

__global__ __launch_bounds__(64) void loss_reduce(const float* __restrict__ partials,
                                                  float* __restrict__ out) {
    float v = partials[threadIdx.x];
    #pragma unroll
    for (int o = 32; o; o >>= 1) v += __shfl_xor(v, o);
    if (threadIdx.x == 0) out[0] = -v;
}

__global__ void sentinel(float* __restrict__ out, float v) { out[0] = -v; }

// ---------------- host ----------------
extern "C" void kernel_launch(void* const* d_in, const int* in_sizes, int n_in,
                              void* d_out, int out_size, void* d_ws, size_t ws_size,
                              hipStream_t stream) {
    const int*   ids      = (const int*)d_in[0];
    const int*   labels   = (const int*)d_in[1];
    const float* emb      = (const float*)d_in[2];
    const float* wih[4]   = { (const float*)d_in[3], (const float*)d_in[7], (const float*)d_in[11], (const float*)d_in[15] };
    const float* whh[4]   = { (const float*)d_in[4], (const float*)d_in[8], (const float*)d_in[12], (const float*)d_in[16] };
    const float* bih[4]   = { (const float*)d_in[5], (const float*)d_in[9], (const float*)d_in[13], (const float*)d_in[17] };
    const float* bhh[4]   = { (const float*)d_in[6], (const float*)d_in[10], (const float*)d_in[14], (const float*)d_in[18] };
    const float* cls_w    = (const float*)d_in[19];
    const float* cls_b    = (const float*)d_in[20];
    const float* c_start  = (const float*)d_in[21];
    const float* c_end    = (const float*)d_in[22];
    const float* c_trans  = (const float*)d_in[23];
    float* out = (float*)d_out;
    float* out1 = out + 1;

    char* p = (char*)d_ws;
    size_t used = 0;
    auto alloc = [&](size_t bytes) -> char* {
        char* r = p;
        size_t a = (bytes + 255) & ~(size_t)255;
        p += a; used += a;
        return r;
    };
    unsigned short* xpF[2]; unsigned short* xpB[2];
    for (int i = 0; i < 2; ++i) {
        xpF[i] = (unsigned short*)alloc((size_t)B_ * TC_ * G_ * 2);   // 12.6MB each
        xpB[i] = (unsigned short*)alloc((size_t)B_ * TC_ * G_ * 2);
    }
    unsigned short* h1   = (unsigned short*)alloc((size_t)BT_ * H2_ * 2);       // 67MB
    unsigned short* gof  = (unsigned short*)alloc((size_t)B_ * TC_ * H_ * 2);   // 4.2MB
    unsigned short* gob  = (unsigned short*)alloc((size_t)B_ * TC_ * H_ * 2);
    unsigned short* clsf  = (unsigned short*)alloc((size_t)32 * H_ * 2);
    unsigned short* clshb = (unsigned short*)alloc((size_t)32 * H_ * 2);
    ull*            hpub  = (ull*)alloc((size_t)2 * 2 * B_ * 256 * 8);          // 1MB tagged
    float*          hcar  = (float*)alloc((size_t)2 * B_ * H_ * 4);             // 256KB
    float*          partials = (float*)alloc((size_t)B_ * 4);
    int*            flags = (int*)alloc((size_t)2 * 4 * 8 * 32 * 4);            // 8KB

    if (used > ws_size) {
        sentinel<<<dim3(1), dim3(1), 0, stream>>>(out, (float)(ws_size >> 20));
        return;
    }

    hipMemsetAsync(flags, 0, (size_t)2 * 4 * 8 * 32 * 4, stream);
    cvt_cls<<<dim3((32 * H_ + 255) / 256), dim3(256), 0, stream>>>(cls_w, clsf, clshb);
    emis_bias_init<<<dim3(1024), dim3(256), 0, stream>>>(cls_b, out1);

    for (int layer = 0; layer < 2; ++layer) {
        const float* wf  = wih[layer * 2 + 0];
        const float* wb  = wih[layer * 2 + 1];
        const float* bf_ = bih[layer * 2 + 0];
        const float* bb_ = bih[layer * 2 + 1];
        const float* whf = whh[layer * 2 + 0];
        const float* whb = whh[layer * 2 + 1];
        const float* bhf = bhh[layer * 2 + 0];
        const float* bhb = bhh[layer * 2 + 1];

        // chunk-0 xp GEMMs (standalone, full grid)
        if (layer == 0) {
            gemm_k<false, false, true, true><<<dim3(64, 24), dim3(256), 0, stream>>>(
                nullptr, emb, ids, E_, 0, T_, wf, E_, G_, bf_, (void*)xpF[0], G_, 0, TC_, G_, E_);
            gemm_k<false, false, true, true><<<dim3(64, 24), dim3(256), 0, stream>>>(
                nullptr, emb, ids, E_, T_ - TC_, T_, wb, E_, G_, bb_, (void*)xpB[0], G_, 0, TC_, G_, E_);
        } else {
            gemm_k<false, false, true, false><<<dim3(64, 24), dim3(256), 0, stream>>>(
                h1, nullptr, nullptr, H2_, 0, T_, wf, H2_, G_, bf_, (void*)xpF[0], G_, 0, TC_, G_, H2_);
            gemm_k<false, false, true, false><<<dim3(64, 24), dim3(256), 0, stream>>>(
                h1, nullptr, nullptr, H2_, T_ - TC_, T_, wb, H2_, G_, bb_, (void*)xpB[0], G_, 0, TC_, G_, H2_);
        }

        for (int c = 0; c < NC_; ++c) {
            int dg = (c + 1 < NC_) ? 1 : 0;
            int t0f_n = (c + 1) * TC_;
            int t0b_n = T_ - (c + 2) * TC_;
            if (layer == 0) {
                fused_scan_gemm<true><<<dim3(256), dim3(256), 0, stream>>>(
                    c, 0, xpF[c & 1], xpB[c & 1], whf, whb, bhf, bhb, hpub, hcar,
                    h1, h1 + H_, H2_, 0, flags,
                    nullptr, emb, ids, E_, wf, wb, bf_, bb_,
                    xpF[(c + 1) & 1], xpB[(c + 1) & 1], t0f_n, t0b_n, dg);
            } else {
                fused_scan_gemm<false><<<dim3(256), dim3(256), 0, stream>>>(
                    c, 1, xpF[c & 1], xpB[c & 1], whf, whb, bhf, bhb, hpub, hcar,
                    gof, gob, H_, 1, flags,
                    h1, nullptr, nullptr, H2_, wf, wb, bf_, bb_,
                    xpF[(c + 1) & 1], xpB[(c + 1) & 1], t0f_n, t0b_n, dg);
                // emissions for this chunk (+= into out1)
                int t0f = c * TC_;
                int t0b = T_ - (c + 1) * TC_;
                gemm_k<true, true, false, false><<<dim3(64, 1), dim3(256), 0, stream>>>(
                    gof, nullptr, nullptr, H_, 0, TC_, clsf, H_, 32, nullptr,
                    (void*)out1, K_, t0f, T_, K_, H_);
                gemm_k<true, true, false, false><<<dim3(64, 1), dim3(256), 0, stream>>>(
                    gob, nullptr, nullptr, H_, 0, TC_, clshb, H_, 32, nullptr,
                    (void*)out1, K_, t0b, T_, K_, H_);
            }
        }
    }

    crf_kernel<<<dim3(B_), dim3(64), 0, stream>>>(out1, labels, c_start, c_end, c_trans, partials);
    loss_reduce<<<dim3(1), dim3(64), 0, stream>>>(partials, out);
}

// Round 11
// 4322.205 us; speedup vs baseline: 6.8108x; 1.4781x over previous
//
#include <hip/hip_runtime.h>

#define DI __device__ __forceinline__

constexpr int B_  = 64;
constexpr int T_  = 512;
constexpr int E_  = 256;
constexpr int H_  = 512;
constexpr int G_  = 1536;   // 3*H
constexpr int H2_ = 1024;   // 2*H
constexpr int K_  = 31;
constexpr int BT_ = B_ * T_;
constexpr int TC_ = 64;     // time-chunk length
constexpr int NC_ = T_ / TC_;

typedef float        f32x4  __attribute__((ext_vector_type(4)));
typedef short        bf16x8 __attribute__((ext_vector_type(8)));
typedef unsigned int u32x4  __attribute__((ext_vector_type(4)));
typedef unsigned long long ull;

DI float bf2f(unsigned short u) {
    union { unsigned int i; float f; } v; v.i = ((unsigned int)u) << 16; return v.f;
}
DI unsigned short f2bf(float f) {
    union { float f; unsigned int i; } v; v.f = f;
    unsigned int r = v.i + 0x7fffu + ((v.i >> 16) & 1u);
    return (unsigned short)(r >> 16);
}
DI float sigm(float x) { return 1.f / (1.f + __expf(-x)); }
DI float tanh_(float x) {
    x = fminf(15.f, fmaxf(-15.f, x));
    float e = __expf(-2.f * x);
    return (1.f - e) / (1.f + e);
}

#define MFMA16(a, b, c) __builtin_amdgcn_mfma_f32_16x16x32_bf16(a, b, c, 0, 0, 0)

// ---------------- fp32 -> bf16 convert ----------------
__global__ void cvt_f32_bf16(const float* __restrict__ src, unsigned short* __restrict__ dst, int n) {
    int i = blockIdx.x * blockDim.x + threadIdx.x;
    int stride = gridDim.x * blockDim.x;
    for (; i < n; i += stride) dst[i] = f2bf(src[i]);
}

// classifier weight split halves -> bf16, pad rows 31.. with zeros
__global__ __launch_bounds__(256) void cvt_cls(const float* __restrict__ src,
                                               unsigned short* __restrict__ dstf,
                                               unsigned short* __restrict__ dstb) {
    int i = blockIdx.x * 256 + threadIdx.x;          // [0, 32*512)
    if (i >= 32 * H_) return;
    int n = i >> 9, k = i & 511;
    float vf = (n < K_) ? src[n * H2_ + k] : 0.f;
    float vb = (n < K_) ? src[n * H2_ + H_ + k] : 0.f;
    dstf[i] = f2bf(vf);
    dstb[i] = f2bf(vb);
}

// emissions bias pre-fill (makes later += replay-deterministic)
__global__ __launch_bounds__(256) void emis_bias_init(const float* __restrict__ cls_b,
                                                      float* __restrict__ out1) {
    int i = blockIdx.x * 256 + threadIdx.x;
    int stride = gridDim.x * 256;
    for (; i < BT_ * K_; i += stride) {
        int n = i - (i / K_) * K_;
        out1[i] = cls_b[n];
    }
}

// ---------------- shared GEMM tile body (256 threads) ----------------
template <bool OUTF32, bool ACCUM, bool WF32, bool AGATHER>
DI void gemm_tile(unsigned short (*As)[40], unsigned short (*Ws)[40],
                  const unsigned short* A, const float* gsrc, const int* ids, int lda,
                  size_t arow0, const void* W, int ldw, int nrows, int n0,
                  const float* bias, void* Cout, int ldc, size_t crow0,
                  int nout, int ksz, int tid) {
    const int w = tid >> 6, l = tid & 63;
    const int srow = tid >> 2, sc8 = (tid & 3) * 8;
    const int mw = (w >> 1) * 32, nw = (w & 1) * 32;
    const int fl = l & 15, fk = (l >> 4) * 8;
    f32x4 z4 = { 0.f, 0.f, 0.f, 0.f };
    f32x4 acc[2][2];
    acc[0][0] = z4; acc[0][1] = z4; acc[1][0] = z4; acc[1][1] = z4;
    size_t abase;
    if (AGATHER) abase = (size_t)ids[arow0 + srow] * lda;
    else         abase = (arow0 + srow) * (size_t)lda;

    for (int kc = 0; kc < ksz; kc += 32) {
        u32x4 av, wvv;
        if (AGATHER) {
            const float4* ap = (const float4*)(gsrc + abase + kc + sc8);
            float4 a0 = ap[0], a1 = ap[1];
            union { unsigned short s[8]; u32x4 v; } r;
            r.s[0] = f2bf(a0.x); r.s[1] = f2bf(a0.y); r.s[2] = f2bf(a0.z); r.s[3] = f2bf(a0.w);
            r.s[4] = f2bf(a1.x); r.s[5] = f2bf(a1.y); r.s[6] = f2bf(a1.z); r.s[7] = f2bf(a1.w);
            av = r.v;
        } else {
            av = *(const u32x4*)(A + abase + kc + sc8);
        }
        if (WF32) {
            const float4* wp = (const float4*)((const float*)W + (size_t)(n0 + srow) * ldw + kc + sc8);
            float4 w0 = wp[0], w1 = wp[1];
            union { unsigned short s[8]; u32x4 v; } r;
            r.s[0] = f2bf(w0.x); r.s[1] = f2bf(w0.y); r.s[2] = f2bf(w0.z); r.s[3] = f2bf(w0.w);
            r.s[4] = f2bf(w1.x); r.s[5] = f2bf(w1.y); r.s[6] = f2bf(w1.z); r.s[7] = f2bf(w1.w);
            wvv = r.v;
        } else {
            if (n0 + srow < nrows)
                wvv = *(const u32x4*)((const unsigned short*)W + (size_t)(n0 + srow) * ldw + kc + sc8);
            else { u32x4 zz = { 0u, 0u, 0u, 0u }; wvv = zz; }
        }
        __syncthreads();
        *(u32x4*)&As[srow][sc8] = av;
        *(u32x4*)&Ws[srow][sc8] = wvv;
        __syncthreads();
        bf16x8 a0 = *(const bf16x8*)&As[mw + fl][fk];
        bf16x8 a1 = *(const bf16x8*)&As[mw + 16 + fl][fk];
        bf16x8 b0 = *(const bf16x8*)&Ws[nw + fl][fk];
        bf16x8 b1 = *(const bf16x8*)&Ws[nw + 16 + fl][fk];
        acc[0][0] = MFMA16(a0, b0, acc[0][0]);
        acc[0][1] = MFMA16(a0, b1, acc[0][1]);
        acc[1][0] = MFMA16(a1, b0, acc[1][0]);
        acc[1][1] = MFMA16(a1, b1, acc[1][1]);
    }

    #pragma unroll
    for (int mf = 0; mf < 2; ++mf)
        #pragma unroll
        for (int nf = 0; nf < 2; ++nf) {
            int col = n0 + nw + nf * 16 + fl;
            if (col >= nout) continue;
            float bv = bias ? bias[col] : 0.f;
            #pragma unroll
            for (int j = 0; j < 4; ++j) {
                int r = mw + mf * 16 + (l >> 4) * 4 + j;
                size_t crow = crow0 + r;
                float v = acc[mf][nf][j] + bv;
                if (OUTF32) {
                    float* C = (float*)Cout;
                    if (ACCUM) C[crow * ldc + col] += v;
                    else       C[crow * ldc + col] = v;
                } else {
                    ((unsigned short*)Cout)[crow * ldc + col] = f2bf(v);
                }
            }
        }
}

template <bool OUTF32, bool ACCUM, bool WF32, bool AGATHER>
__global__ __launch_bounds__(256) void gemm_k(
        const unsigned short* __restrict__ A, const float* __restrict__ gsrc,
        const int* __restrict__ ids, int lda, int m_base, int astride,
        const void* __restrict__ W, int ldw, int nrows,
        const float* __restrict__ bias,
        void* __restrict__ Cout, int ldc, int c_base, int cstride, int nout, int ksz) {
    __shared__ unsigned short As[64][40];
    __shared__ unsigned short Ws[64][40];
    gemm_tile<OUTF32, ACCUM, WF32, AGATHER>(As, Ws, A, gsrc, ids, lda,
        (size_t)m_base + (size_t)blockIdx.x * astride, W, ldw, nrows,
        blockIdx.y * 64, bias, Cout, ldc,
        (size_t)c_base + (size_t)blockIdx.x * cstride, nout, ksz, threadIdx.x);
}

// merged emissions: grid (64,2); y=0 -> gof half, y=1 -> gob half. += into out1.
__global__ __launch_bounds__(256) void emis_k(
        const unsigned short* __restrict__ gof, const unsigned short* __restrict__ gob,
        const unsigned short* __restrict__ clsf, const unsigned short* __restrict__ clsb,
        float* __restrict__ out1, int t0f, int t0b) {
    __shared__ unsigned short As[64][40];
    __shared__ unsigned short Ws[64][40];
    const unsigned short* A = blockIdx.y ? gob : gof;
    const unsigned short* W = blockIdx.y ? clsb : clsf;
    int t0 = blockIdx.y ? t0b : t0f;
    gemm_tile<true, true, false, false>(As, Ws, A, nullptr, nullptr, H_,
        (size_t)blockIdx.x * TC_, W, H_, 32, 0, nullptr,
        (void*)out1, K_, (size_t)t0 + (size_t)blockIdx.x * T_, K_, H_, threadIdx.x);
}

// ---------------- fused: persistent GRU scan (blocks 0-63) + next-chunk xp GEMM ----------------
// Round-8 proven structure: per dir 32 blocks = 8 unit-groups x 4 batch-groups
// (16 batches). Sync group = 8 blocks (same dir,bg). Per step: poll 8 flags ->
// cooperative 16KB LDS stage of h(s-1) (atomic agent loads, XOR-swizzled) ->
// sync -> 48 MFMA/wave (bf16 W in VGPRs) -> gates -> packed h stores ->
// counted drain (vmcnt(16): waits ONLY the 4 h stores; outp+xp prefetch issue
// under the ack RT) -> raw s_barrier (no compiler vmcnt(0) drain) -> flag.
// Flags zeroed per call, monotone targets -> replay-deterministic.
template <bool AGATHER>
__global__ __launch_bounds__(256, 1) void fused_scan_gemm(
        int c, int layer,
        const unsigned short* __restrict__ xpc_f, const unsigned short* __restrict__ xpc_b,
        const unsigned short* __restrict__ whh_f, const unsigned short* __restrict__ whh_b,
        const float* __restrict__ bhh_f, const float* __restrict__ bhh_b,
        unsigned int* __restrict__ hpub,    // [parity][dir][B][256] u32 (2 packed bf16)
        float* __restrict__ hcar,           // [dir][B][H] f32 chunk-carry
        unsigned short* __restrict__ out_f, unsigned short* __restrict__ out_b,
        int ldo, int mode, int* __restrict__ flags,
        const unsigned short* __restrict__ gA, const float* __restrict__ gsrc,
        const int* __restrict__ gids, int glda,
        const float* __restrict__ gwf, const float* __restrict__ gwb,
        const float* __restrict__ gbf, const float* __restrict__ gbb,
        unsigned short* __restrict__ xpf_nxt, unsigned short* __restrict__ xpb_nxt,
        int t0f_n, int t0b_n, int do_gemm) {
    __shared__ unsigned short As[64][40];
    __shared__ unsigned short Ws[64][40];
    __shared__ unsigned short hs[16 * 512];          // 16KB staged h(s-1), swizzled
    const int bid = blockIdx.x;
    const int tid = threadIdx.x;

    if (bid >= 64) {                       // ---- GEMM blocks: next chunk's xp ----
        if (!do_gemm) return;
        const int gb = bid - 64;
        for (int job = gb; job < 2 * 64 * 24; job += 192) {
            int dirj = job & 1;
            int rest = job >> 1;
            int mt = rest & 63;            // batch
            int nt = rest >> 6;            // n-tile [0,24)
            const float* gw = dirj ? gwb : gwf;
            const float* gbias = dirj ? gbb : gbf;
            unsigned short* gout = dirj ? xpb_nxt : xpf_nxt;
            int t0 = dirj ? t0b_n : t0f_n;
            gemm_tile<false, false, true, AGATHER>(As, Ws, gA, gsrc, gids, glda,
                (size_t)t0 + (size_t)mt * T_, gw, glda, G_, nt * 64, gbias,
                (void*)gout, G_, (size_t)mt * TC_, G_, glda, tid);
        }
        return;
    }

    // ---- scan blocks ----
    const int dir = bid >> 5;
    const int rb  = bid & 31;
    const int ug  = rb >> 2;               // unit-group [0,8)
    const int bg  = rb & 3;                // batch-group [0,4)
    const int w = tid >> 6, l = tid & 63;
    const int fl = l & 15, q = l >> 4, fko = q * 8;
    const unsigned short* xp = dir ? xpc_b : xpc_f;
    const unsigned short* whh = dir ? whh_b : whh_f;   // bf16
    const float* bhh = dir ? bhh_b : bhh_f;
    unsigned short* outp = dir ? out_b : out_f;
    int* pollb  = flags + (dir * 4 + bg) * 8 * 32;   // 8 flags, 128B apart
    int* myflag = pollb + ug * 32;

    // W_hh (bf16) -> VGPR fragments, once per chunk
    const int u0w = ug * 64 + w * 16;
    bf16x8 wv[3][16];
    #pragma unroll
    for (int g = 0; g < 3; ++g)
        #pragma unroll
        for (int ks = 0; ks < 16; ++ks)
            wv[g][ks] = *(const bf16x8*)(whh + (size_t)(g * H_ + u0w + fl) * H_ + ks * 32 + fko);

    const int u = u0w + fl;
    const float br_ = bhh[u], bz_ = bhh[H_ + u], bn_ = bhh[2 * H_ + u];
    const int mb = bg * 16 + q * 4;        // epilogue batch base (4 rows)
    const int srowl = tid >> 4;            // stage: local row [0,16)
    const int sseg  = tid & 15;            // stage: 64B segment

    float hp[4];
    if (c > 0) {
        #pragma unroll
        for (int j = 0; j < 4; ++j) hp[j] = hcar[dir * (B_ * H_) + (mb + j) * H_ + u];
    } else {
        #pragma unroll
        for (int j = 0; j < 4; ++j) hp[j] = 0.f;
    }

    unsigned short xg[3][4];
    auto ldxp = [&](int tl) {
        #pragma unroll
        for (int j = 0; j < 4; ++j) {
            const unsigned short* xb = xp + ((size_t)((mb + j) * TC_ + tl) * G_) + u;
            xg[0][j] = xb[0]; xg[1][j] = xb[H_]; xg[2][j] = xb[2 * H_];
        }
    };
    ldxp(dir ? (TC_ - 1) : 0);

    for (int sl = 0; sl < TC_; ++sl) {
        const int s  = c * TC_ + sl;
        const int gs = layer * T_ + s;
        const int t = dir ? (T_ - 1 - s) : s;
        const int tloc = dir ? (TC_ - 1 - sl) : sl;

        f32x4 z4 = { 0.f, 0.f, 0.f, 0.f };
        f32x4 acc[3];
        acc[0] = z4; acc[1] = z4; acc[2] = z4;

        if (s > 0) {
            if (sl > 0) {                  // chunk start: prev launch done via stream order
                int v = gs;
                if (l < 8) v = __hip_atomic_load(pollb + l * 32, __ATOMIC_RELAXED, __HIP_MEMORY_SCOPE_AGENT);
                while (!__all(v >= gs)) {
                    __builtin_amdgcn_s_sleep(1);
                    if (l < 8) v = __hip_atomic_load(pollb + l * 32, __ATOMIC_RELAXED, __HIP_MEMORY_SCOPE_AGENT);
                }
                asm volatile("" ::: "memory");   // no hoist of h loads above poll
            }
            // cooperative stage: h(s-1)[bg*16 .. +15][all 512] -> LDS (swizzled)
            {
                const ull* src = (const ull*)(hpub
                    + ((size_t)((((s - 1) & 1) * 2 + dir) * B_ + bg * 16 + srowl)) * 256)
                    + sseg * 8;
                ull qv[8];
                #pragma unroll
                for (int i = 0; i < 8; ++i)
                    qv[i] = __hip_atomic_load(src + i, __ATOMIC_RELAXED, __HIP_MEMORY_SCOPE_AGENT);
                char* dst = (char*)hs + srowl * 1024;
                #pragma unroll
                for (int i = 0; i < 4; ++i) {
                    unsigned int byt = (unsigned int)(sseg * 64 + i * 16);
                    byt ^= ((unsigned int)(srowl & 7)) << 4;
                    union { ull qq[2]; u32x4 v4; } pk;
                    pk.qq[0] = qv[2 * i]; pk.qq[1] = qv[2 * i + 1];
                    *(u32x4*)(dst + byt) = pk.v4;
                }
            }
            __syncthreads();
            #pragma unroll
            for (int ks = 0; ks < 16; ++ks) {
                unsigned int byt = (unsigned int)(ks * 64 + q * 16);
                byt ^= ((unsigned int)(fl & 7)) << 4;
                bf16x8 afr = *(const bf16x8*)((const char*)hs + fl * 1024 + byt);
                acc[0] = MFMA16(afr, wv[0][ks], acc[0]);
                acc[1] = MFMA16(afr, wv[1][ks], acc[1]);
                acc[2] = MFMA16(afr, wv[2][ks], acc[2]);
            }
        }

        unsigned short hb16s[4];
        #pragma unroll
        for (int j = 0; j < 4; ++j) {
            float xr = bf2f(xg[0][j]);
            float xz = bf2f(xg[1][j]);
            float xn = bf2f(xg[2][j]);
            float r = sigm(xr + acc[0][j] + br_);
            float z = sigm(xz + acc[1][j] + bz_);
            float nn = tanh_(xn + r * (acc[2][j] + bn_));
            float hv = (1.f - z) * nn + z * hp[j];
            hp[j] = hv;
            hb16s[j] = f2bf(hv);
        }

        // packed h stores (even-fl lanes) FIRST ...
        unsigned int* hw = hpub + (size_t)((s & 1) * 2 + dir) * (B_ * 256);
        #pragma unroll
        for (int j = 0; j < 4; ++j) {
            unsigned int pv = (unsigned int)(unsigned short)__shfl_xor((int)hb16s[j], 1);
            if ((fl & 1) == 0) {
                unsigned int pk32 = (unsigned int)hb16s[j] | (pv << 16);
                __hip_atomic_store(hw + (size_t)(mb + j) * 256 + (u >> 1), pk32,
                                   __ATOMIC_RELAXED, __HIP_MEMORY_SCOPE_AGENT);
            }
        }
        asm volatile("" ::: "memory");     // pin issue order: h stores before the 16 below
        // ... then outp stores + next-xp prefetch issue UNDER the h-store ack RT
        #pragma unroll
        for (int j = 0; j < 4; ++j) {
            size_t row = mode ? (size_t)((mb + j) * TC_ + tloc) : ((size_t)(mb + j) * T_ + t);
            outp[row * ldo + u] = hb16s[j];
        }
        if (sl < TC_ - 1) ldxp(dir ? (TC_ - 2 - sl) : (sl + 1));
        // counted wait: <=16 outstanding => the 4 older h stores are acked
        asm volatile("s_waitcnt vmcnt(16)" ::: "memory");
        __builtin_amdgcn_s_barrier();      // raw barrier: no compiler vmcnt(0) drain
        if (tid == 0)
            __hip_atomic_store(myflag, gs + 1, __ATOMIC_RELAXED, __HIP_MEMORY_SCOPE_AGENT);
    }

    #pragma unroll
    for (int j = 0; j < 4; ++j) hcar[dir * (B_ * H_) + (mb + j) * H_ + u] = hp[j];
}

// ---------------- CRF: one block (one wave) per batch element ----------------
__global__ __launch_bounds__(64) void crf_kernel(const float* __restrict__ em,     // [BT][K]
                                                 const int* __restrict__ labels,
                                                 const float* __restrict__ start,
                                                 const float* __restrict__ endv,
                                                 const float* __restrict__ trans,
                                                 float* __restrict__ partials) {
    __shared__ float tr[32 * 32];
    const int b = blockIdx.x, l = threadIdx.x;
    for (int e2 = l; e2 < 961; e2 += 64) {
        int r = e2 / 31, cc = e2 - r * 31;
        tr[r * 32 + cc] = trans[e2];
    }
    if (l < 32) tr[31 * 32 + l] = 0.f;
    __syncthreads();
    const int* lab = labels + b * T_;
    const float* eb = em + (size_t)b * T_ * K_;

    float part = 0.f, cnt = 0.f;
    for (int t = l; t < T_; t += 64) {
        int lt = lab[t];
        if (lt > -1) {
            cnt += 1.f;
            if (t > 0) part += tr[lab[t - 1] * 32 + lt] + eb[t * K_ + lt];
        }
    }
    #pragma unroll
    for (int o = 32; o; o >>= 1) { part += __shfl_xor(part, o); cnt += __shfl_xor(cnt, o); }
    int lastidx = (int)cnt - 1;
    float num = part + start[lab[0]] + eb[lab[0]] + endv[lab[lastidx]];

    const int jj = l & 31, half = l >> 5;
    const int i0 = half * 16;
    const int ecol = (jj < K_) ? jj : (K_ - 1);
    float a = (jj < K_) ? (start[jj] + eb[jj]) : -3.0e38f;
    for (int t = 1; t < T_; ++t) {
        float tv[16];
        float m = -3.0e38f;
        #pragma unroll
        for (int k = 0; k < 16; ++k) {
            float av = __shfl(a, i0 + k);
            float x = av + tr[(i0 + k) * 32 + jj];
            tv[k] = x;
            m = fmaxf(m, x);
        }
        float ss = 0.f;
        #pragma unroll
        for (int k = 0; k < 16; ++k) ss += __expf(tv[k] - m);
        float m2 = __shfl_xor(m, 32), s2 = __shfl_xor(ss, 32);
        float M = fmaxf(m, m2);
        float S = ss * __expf(m - M) + s2 * __expf(m2 - M);
        float anew = eb[t * K_ + ecol] + M + __logf(S);
        a = ((lab[t] > -1) && (jj < K_)) ? anew : a;
    }
    float v = (jj < K_) ? (a + endv[jj]) : -3.0e38f;
    float m = v;
    #pragma unroll
    for (int o = 32; o; o >>= 1) m = fmaxf(m, __shfl_xor(m, o));
    float ss = (half == 0 && jj < K_) ? __expf(v - m) : 0.f;
    #pragma unroll
    for (int o = 32; o; o >>= 1) ss += __shfl_xor(ss, o);
    if (l == 0) partials[b] = num - (m + __logf(ss));
}

__global__ __launch_bounds__(64) void loss_reduce(const float* __restrict__ partials,
                                                  float* __restrict__ out) {
    float v = partials[threadIdx.x];
    #pragma unroll
    for (int o = 32; o; o >>= 1) v += __shfl_xor(v, o);
    if (threadIdx.x == 0) out[0] = -v;
}

__global__ void sentinel(float* __restrict__ out, float v) { out[0] = -v; }

// ---------------- host ----------------
extern "C" void kernel_launch(void* const* d_in, const int* in_sizes, int n_in,
                              void* d_out, int out_size, void* d_ws, size_t ws_size,
                              hipStream_t stream) {
    const int*   ids      = (const int*)d_in[0];
    const int*   labels   = (const int*)d_in[1];
    const float* emb      = (const float*)d_in[2];
    const float* wih[4]   = { (const float*)d_in[3], (const float*)d_in[7], (const float*)d_in[11], (const float*)d_in[15] };
    const float* whh[4]   = { (const float*)d_in[4], (const float*)d_in[8], (const float*)d_in[12], (const float*)d_in[16] };
    const float* bih[4]   = { (const float*)d_in[5], (const float*)d_in[9], (const float*)d_in[13], (const float*)d_in[17] };
    const float* bhh[4]   = { (const float*)d_in[6], (const float*)d_in[10], (const float*)d_in[14], (const float*)d_in[18] };
    const float* cls_w    = (const float*)d_in[19];
    const float* cls_b    = (const float*)d_in[20];
    const float* c_start  = (const float*)d_in[21];
    const float* c_end    = (const float*)d_in[22];
    const float* c_trans  = (const float*)d_in[23];
    float* out = (float*)d_out;
    float* out1 = out + 1;

    char* p = (char*)d_ws;
    size_t used = 0;
    auto alloc = [&](size_t bytes) -> char* {
        char* r = p;
        size_t a = (bytes + 255) & ~(size_t)255;
        p += a; used += a;
        return r;
    };
    unsigned short* xpF[2]; unsigned short* xpB[2];
    for (int i = 0; i < 2; ++i) {
        xpF[i] = (unsigned short*)alloc((size_t)B_ * TC_ * G_ * 2);   // 12.6MB each
        xpB[i] = (unsigned short*)alloc((size_t)B_ * TC_ * G_ * 2);
    }
    unsigned short* h1   = (unsigned short*)alloc((size_t)BT_ * H2_ * 2);       // 67MB
    unsigned short* gof  = (unsigned short*)alloc((size_t)B_ * TC_ * H_ * 2);   // 4.2MB
    unsigned short* gob  = (unsigned short*)alloc((size_t)B_ * TC_ * H_ * 2);
    unsigned short* clsf  = (unsigned short*)alloc((size_t)32 * H_ * 2);
    unsigned short* clshb = (unsigned short*)alloc((size_t)32 * H_ * 2);
    unsigned short* whhbf = (unsigned short*)alloc((size_t)G_ * H_ * 2);        // 1.57MB (per-layer, re-cvt)
    unsigned short* whhbb = (unsigned short*)alloc((size_t)G_ * H_ * 2);
    unsigned int*   hpub  = (unsigned int*)alloc((size_t)2 * 2 * B_ * 256 * 4); // 512KB
    float*          hcar  = (float*)alloc((size_t)2 * B_ * H_ * 4);             // 256KB
    float*          partials = (float*)alloc((size_t)B_ * 4);
    int*            flags = (int*)alloc((size_t)2 * 4 * 8 * 32 * 4);            // 8KB

    if (used > ws_size) {
        sentinel<<<dim3(1), dim3(1), 0, stream>>>(out, (float)(ws_size >> 20));
        return;
    }

    hipMemsetAsync(flags, 0, (size_t)2 * 4 * 8 * 32 * 4, stream);
    cvt_cls<<<dim3((32 * H_ + 255) / 256), dim3(256), 0, stream>>>(cls_w, clsf, clshb);
    emis_bias_init<<<dim3(1024), dim3(256), 0, stream>>>(cls_b, out1);

    for (int layer = 0; layer < 2; ++layer) {
        const float* wf  = wih[layer * 2 + 0];
        const float* wb  = wih[layer * 2 + 1];
        const float* bf_ = bih[layer * 2 + 0];
        const float* bb_ = bih[layer * 2 + 1];
        const float* bhf = bhh[layer * 2 + 0];
        const float* bhb = bhh[layer * 2 + 1];

        // convert this layer's W_hh pair -> bf16 (stream-ordered, deterministic)
        cvt_f32_bf16<<<dim3(2048), dim3(256), 0, stream>>>(whh[layer * 2 + 0], whhbf, G_ * H_);
        cvt_f32_bf16<<<dim3(2048), dim3(256), 0, stream>>>(whh[layer * 2 + 1], whhbb, G_ * H_);

        // chunk-0 xp GEMMs (standalone, full grid)
        if (layer == 0) {
            gemm_k<false, false, true, true><<<dim3(64, 24), dim3(256), 0, stream>>>(
                nullptr, emb, ids, E_, 0, T_, wf, E_, G_, bf_, (void*)xpF[0], G_, 0, TC_, G_, E_);
            gemm_k<false, false, true, true><<<dim3(64, 24), dim3(256), 0, stream>>>(
                nullptr, emb, ids, E_, T_ - TC_, T_, wb, E_, G_, bb_, (void*)xpB[0], G_, 0, TC_, G_, E_);
        } else {
            gemm_k<false, false, true, false><<<dim3(64, 24), dim3(256), 0, stream>>>(
                h1, nullptr, nullptr, H2_, 0, T_, wf, H2_, G_, bf_, (void*)xpF[0], G_, 0, TC_, G_, H2_);
            gemm_k<false, false, true, false><<<dim3(64, 24), dim3(256), 0, stream>>>(
                h1, nullptr, nullptr, H2_, T_ - TC_, T_, wb, H2_, G_, bb_, (void*)xpB[0], G_, 0, TC_, G_, H2_);
        }

        for (int c = 0; c < NC_; ++c) {
            int dg = (c + 1 < NC_) ? 1 : 0;
            int t0f_n = (c + 1) * TC_;
            int t0b_n = T_ - (c + 2) * TC_;
            if (layer == 0) {
                fused_scan_gemm<true><<<dim3(256), dim3(256), 0, stream>>>(
                    c, 0, xpF[c & 1], xpB[c & 1], whhbf, whhbb, bhf, bhb, hpub, hcar,
                    h1, h1 + H_, H2_, 0, flags,
                    nullptr, emb, ids, E_, wf, wb, bf_, bb_,
                    xpF[(c + 1) & 1], xpB[(c + 1) & 1], t0f_n, t0b_n, dg);
            } else {
                fused_scan_gemm<false><<<dim3(256), dim3(256), 0, stream>>>(
                    c, 1, xpF[c & 1], xpB[c & 1], whhbf, whhbb, bhf, bhb, hpub, hcar,
                    gof, gob, H_, 1, flags,
                    h1, nullptr, nullptr, H2_, wf, wb, bf_, bb_,
                    xpF[(c + 1) & 1], xpB[(c + 1) & 1], t0f_n, t0b_n, dg);
                // emissions for this chunk (merged pair, += into out1)
                int t0f = c * TC_;
                int t0b = T_ - (c + 1) * TC_;
                emis_k<<<dim3(64, 2), dim3(256), 0, stream>>>(gof, gob, clsf, clshb, out1, t0f, t0b);
            }
        }
    }

    crf_kernel<<<dim3(B_), dim3(64), 0, stream>>>(out1, labels, c_start, c_end, c_trans, partials);
    loss_reduce<<<dim3(1), dim3(64), 0, stream>>>(partials, out);
}

// Round 12
// 4299.723 us; speedup vs baseline: 6.8464x; 1.0052x over previous
//
#include <hip/hip_runtime.h>

#define DI __device__ __forceinline__

constexpr int B_  = 64;
constexpr int T_  = 512;
constexpr int E_  = 256;
constexpr int H_  = 512;
constexpr int G_  = 1536;   // 3*H
constexpr int H2_ = 1024;   // 2*H
constexpr int K_  = 31;
constexpr int BT_ = B_ * T_;
constexpr int TC_ = 64;     // time-chunk length
constexpr int NC_ = T_ / TC_;

typedef float        f32x4  __attribute__((ext_vector_type(4)));
typedef short        bf16x8 __attribute__((ext_vector_type(8)));
typedef unsigned int u32x4  __attribute__((ext_vector_type(4)));
typedef unsigned long long ull;

DI float bf2f(unsigned short u) {
    union { unsigned int i; float f; } v; v.i = ((unsigned int)u) << 16; return v.f;
}
DI unsigned short f2bf(float f) {
    union { float f; unsigned int i; } v; v.f = f;
    unsigned int r = v.i + 0x7fffu + ((v.i >> 16) & 1u);
    return (unsigned short)(r >> 16);
}
DI float sigm(float x) { return 1.f / (1.f + __expf(-x)); }
DI float tanh_(float x) {
    x = fminf(15.f, fmaxf(-15.f, x));
    float e = __expf(-2.f * x);
    return (1.f - e) / (1.f + e);
}

#define MFMA16(a, b, c) __builtin_amdgcn_mfma_f32_16x16x32_bf16(a, b, c, 0, 0, 0)

// ---------------- fp32 -> bf16 convert ----------------
__global__ void cvt_f32_bf16(const float* __restrict__ src, unsigned short* __restrict__ dst, int n) {
    int i = blockIdx.x * blockDim.x + threadIdx.x;
    int stride = gridDim.x * blockDim.x;
    for (; i < n; i += stride) dst[i] = f2bf(src[i]);
}

// classifier weight split halves -> bf16, pad rows 31.. with zeros
__global__ __launch_bounds__(256) void cvt_cls(const float* __restrict__ src,
                                               unsigned short* __restrict__ dstf,
                                               unsigned short* __restrict__ dstb) {
    int i = blockIdx.x * 256 + threadIdx.x;          // [0, 32*512)
    if (i >= 32 * H_) return;
    int n = i >> 9, k = i & 511;
    float vf = (n < K_) ? src[n * H2_ + k] : 0.f;
    float vb = (n < K_) ? src[n * H2_ + H_ + k] : 0.f;
    dstf[i] = f2bf(vf);
    dstb[i] = f2bf(vb);
}

// emissions bias pre-fill (makes later += replay-deterministic)
__global__ __launch_bounds__(256) void emis_bias_init(const float* __restrict__ cls_b,
                                                      float* __restrict__ out1) {
    int i = blockIdx.x * 256 + threadIdx.x;
    int stride = gridDim.x * 256;
    for (; i < BT_ * K_; i += stride) {
        int n = i - (i / K_) * K_;
        out1[i] = cls_b[n];
    }
}

// ---------------- shared GEMM tile body (256 threads, 64x64) ----------------
template <bool OUTF32, bool ACCUM, bool WF32, bool AGATHER>
DI void gemm_tile(unsigned short (*As)[40], unsigned short (*Ws)[40],
                  const unsigned short* A, const float* gsrc, const int* ids, int lda,
                  size_t arow0, const void* W, int ldw, int nrows, int n0,
                  const float* bias, void* Cout, int ldc, size_t crow0,
                  int nout, int ksz, int tid) {
    const int w = tid >> 6, l = tid & 63;
    const int srow = tid >> 2, sc8 = (tid & 3) * 8;
    const int mw = (w >> 1) * 32, nw = (w & 1) * 32;
    const int fl = l & 15, fk = (l >> 4) * 8;
    f32x4 z4 = { 0.f, 0.f, 0.f, 0.f };
    f32x4 acc[2][2];
    acc[0][0] = z4; acc[0][1] = z4; acc[1][0] = z4; acc[1][1] = z4;
    size_t abase;
    if (AGATHER) abase = (size_t)ids[arow0 + srow] * lda;
    else         abase = (arow0 + srow) * (size_t)lda;

    for (int kc = 0; kc < ksz; kc += 32) {
        u32x4 av, wvv;
        if (AGATHER) {
            const float4* ap = (const float4*)(gsrc + abase + kc + sc8);
            float4 a0 = ap[0], a1 = ap[1];
            union { unsigned short s[8]; u32x4 v; } r;
            r.s[0] = f2bf(a0.x); r.s[1] = f2bf(a0.y); r.s[2] = f2bf(a0.z); r.s[3] = f2bf(a0.w);
            r.s[4] = f2bf(a1.x); r.s[5] = f2bf(a1.y); r.s[6] = f2bf(a1.z); r.s[7] = f2bf(a1.w);
            av = r.v;
        } else {
            av = *(const u32x4*)(A + abase + kc + sc8);
        }
        if (WF32) {
            const float4* wp = (const float4*)((const float*)W + (size_t)(n0 + srow) * ldw + kc + sc8);
            float4 w0 = wp[0], w1 = wp[1];
            union { unsigned short s[8]; u32x4 v; } r;
            r.s[0] = f2bf(w0.x); r.s[1] = f2bf(w0.y); r.s[2] = f2bf(w0.z); r.s[3] = f2bf(w0.w);
            r.s[4] = f2bf(w1.x); r.s[5] = f2bf(w1.y); r.s[6] = f2bf(w1.z); r.s[7] = f2bf(w1.w);
            wvv = r.v;
        } else {
            if (n0 + srow < nrows)
                wvv = *(const u32x4*)((const unsigned short*)W + (size_t)(n0 + srow) * ldw + kc + sc8);
            else { u32x4 zz = { 0u, 0u, 0u, 0u }; wvv = zz; }
        }
        __syncthreads();
        *(u32x4*)&As[srow][sc8] = av;
        *(u32x4*)&Ws[srow][sc8] = wvv;
        __syncthreads();
        bf16x8 a0 = *(const bf16x8*)&As[mw + fl][fk];
        bf16x8 a1 = *(const bf16x8*)&As[mw + 16 + fl][fk];
        bf16x8 b0 = *(const bf16x8*)&Ws[nw + fl][fk];
        bf16x8 b1 = *(const bf16x8*)&Ws[nw + 16 + fl][fk];
        acc[0][0] = MFMA16(a0, b0, acc[0][0]);
        acc[0][1] = MFMA16(a0, b1, acc[0][1]);
        acc[1][0] = MFMA16(a1, b0, acc[1][0]);
        acc[1][1] = MFMA16(a1, b1, acc[1][1]);
    }

    #pragma unroll
    for (int mf = 0; mf < 2; ++mf)
        #pragma unroll
        for (int nf = 0; nf < 2; ++nf) {
            int col = n0 + nw + nf * 16 + fl;
            if (col >= nout) continue;
            float bv = bias ? bias[col] : 0.f;
            #pragma unroll
            for (int j = 0; j < 4; ++j) {
                int r = mw + mf * 16 + (l >> 4) * 4 + j;
                size_t crow = crow0 + r;
                float v = acc[mf][nf][j] + bv;
                if (OUTF32) {
                    float* C = (float*)Cout;
                    if (ACCUM) C[crow * ldc + col] += v;
                    else       C[crow * ldc + col] = v;
                } else {
                    ((unsigned short*)Cout)[crow * ldc + col] = f2bf(v);
                }
            }
        }
}

template <bool OUTF32, bool ACCUM, bool WF32, bool AGATHER>
__global__ __launch_bounds__(256) void gemm_k(
        const unsigned short* __restrict__ A, const float* __restrict__ gsrc,
        const int* __restrict__ ids, int lda, int m_base, int astride,
        const void* __restrict__ W, int ldw, int nrows,
        const float* __restrict__ bias,
        void* __restrict__ Cout, int ldc, int c_base, int cstride, int nout, int ksz) {
    __shared__ unsigned short As[64][40];
    __shared__ unsigned short Ws[64][40];
    gemm_tile<OUTF32, ACCUM, WF32, AGATHER>(As, Ws, A, gsrc, ids, lda,
        (size_t)m_base + (size_t)blockIdx.x * astride, W, ldw, nrows,
        blockIdx.y * 64, bias, Cout, ldc,
        (size_t)c_base + (size_t)blockIdx.x * cstride, nout, ksz, threadIdx.x);
}

// merged emissions: grid (64,2); y=0 -> gof half, y=1 -> gob half. += into out1.
__global__ __launch_bounds__(256) void emis_k(
        const unsigned short* __restrict__ gof, const unsigned short* __restrict__ gob,
        const unsigned short* __restrict__ clsf, const unsigned short* __restrict__ clsb,
        float* __restrict__ out1, int t0f, int t0b) {
    __shared__ unsigned short As[64][40];
    __shared__ unsigned short Ws[64][40];
    const unsigned short* A = blockIdx.y ? gob : gof;
    const unsigned short* W = blockIdx.y ? clsb : clsf;
    int t0 = blockIdx.y ? t0b : t0f;
    gemm_tile<true, true, false, false>(As, Ws, A, nullptr, nullptr, H_,
        (size_t)blockIdx.x * TC_, W, H_, 32, 0, nullptr,
        (void*)out1, K_, (size_t)t0 + (size_t)blockIdx.x * T_, K_, H_, threadIdx.x);
}

// ---------------- fused: persistent GRU scan (blocks 0-63) + next-chunk xp GEMM ----------------
// Scan (delta vs r11): per-WAVE producer flags (no block barrier on the flag
// path), 2-parity LDS h-stage (drops the end-of-step barrier; one syncthreads
// per step between stage and MFMA-read). Cross-wave LDS WAR safety is carried
// by the flag chain: re-staging a parity half requires all waves' flags for
// the intervening step, which postdate their reads. GEMM (delta): layer-1
// path is a 128x128 tile (4x4 frags/wave, W-stationary, 4 jobs/block);
// layer-0 keeps the 64x64 gather path.
template <bool AGATHER>
__global__ __launch_bounds__(256, 1) void fused_scan_gemm(
        int c, int layer,
        const unsigned short* __restrict__ xpc_f, const unsigned short* __restrict__ xpc_b,
        const unsigned short* __restrict__ whh_f, const unsigned short* __restrict__ whh_b,
        const float* __restrict__ bhh_f, const float* __restrict__ bhh_b,
        unsigned int* __restrict__ hpub,    // [parity][dir][B][256] u32 (2 packed bf16)
        float* __restrict__ hcar,           // [dir][B][H] f32 chunk-carry
        unsigned short* __restrict__ out_f, unsigned short* __restrict__ out_b,
        int ldo, int mode, int* __restrict__ flags,
        const unsigned short* __restrict__ gA, const float* __restrict__ gsrc,
        const int* __restrict__ gids, int glda,
        const float* __restrict__ gwf, const float* __restrict__ gwb,
        const float* __restrict__ gbf, const float* __restrict__ gbb,
        unsigned short* __restrict__ xpf_nxt, unsigned short* __restrict__ xpb_nxt,
        int t0f_n, int t0b_n, int do_gemm) {
    __shared__ __align__(16) char smem[32768];
    const int bid = blockIdx.x;
    const int tid = threadIdx.x;

    if (bid >= 64) {                       // ---- GEMM blocks ----
        if (!do_gemm) return;
        const int gb = bid - 64;
        if (AGATHER) {
            // layer-0: 64x64 gather path (light)
            unsigned short (*As)[40] = (unsigned short (*)[40])smem;
            unsigned short (*Ws)[40] = (unsigned short (*)[40])(smem + 5120);
            for (int job = gb; job < 2 * 64 * 24; job += 192) {
                int dirj = job & 1;
                int rest = job >> 1;
                int mt = rest & 63;
                int nt = rest >> 6;
                const float* gw = dirj ? gwb : gwf;
                const float* gbias = dirj ? gbb : gbf;
                unsigned short* gout = dirj ? xpb_nxt : xpf_nxt;
                int t0 = dirj ? t0b_n : t0f_n;
                gemm_tile<false, false, true, true>(As, Ws, gA, gsrc, gids, glda,
                    (size_t)t0 + (size_t)mt * T_, gw, glda, G_, nt * 64, gbias,
                    (void*)gout, G_, (size_t)mt * TC_, G_, glda, tid);
            }
        } else {
            // layer-1: 128x128 tile, K=1024, BK=32; 768 jobs = 192 blocks x 4
            unsigned short (*A1)[40] = (unsigned short (*)[40])smem;            // [128][40]
            unsigned short (*W1)[40] = (unsigned short (*)[40])(smem + 10240);  // [128][40]
            const int w = tid >> 6, l = tid & 63;
            const int fl = l & 15, fk = (l >> 4) * 8;
            const int mw2 = (w >> 1) * 64, nw2 = (w & 1) * 64;
            const int rA = tid >> 1, ch = (tid & 1) * 16;   // stage row, col-half
            #pragma unroll 1
            for (int it = 0; it < 4; ++it) {
                int job = gb * 4 + it;         // [0,768)
                int dirj = (job >= 384) ? 1 : 0;
                int jj = job - dirj * 384;
                int nt = jj >> 5;              // [0,12)
                int mt2 = jj & 31;             // [0,32)
                const float* gw = dirj ? gwb : gwf;
                const float* gbias = dirj ? gbb : gbf;
                unsigned short* gout = dirj ? xpb_nxt : xpf_nxt;
                int t0 = dirj ? t0b_n : t0f_n;
                int n0j = nt * 128;
                const int mA = mt2 * 2 + (rA >> 6), tlA = rA & 63;
                const unsigned short* aRow = gA + ((size_t)mA * T_ + t0 + tlA) * H2_ + ch;
                const float* wRow = gw + (size_t)(n0j + rA) * H2_ + ch;
                f32x4 z4 = { 0.f, 0.f, 0.f, 0.f };
                f32x4 acc[4][4];
                #pragma unroll
                for (int a2 = 0; a2 < 4; ++a2)
                    #pragma unroll
                    for (int b2 = 0; b2 < 4; ++b2) acc[a2][b2] = z4;

                for (int kc = 0; kc < H2_; kc += 32) {
                    u32x4 av0 = *(const u32x4*)(aRow + kc);
                    u32x4 av1 = *(const u32x4*)(aRow + kc + 8);
                    float4 w0 = *(const float4*)(wRow + kc);
                    float4 w1 = *(const float4*)(wRow + kc + 4);
                    float4 w2 = *(const float4*)(wRow + kc + 8);
                    float4 w3 = *(const float4*)(wRow + kc + 12);
                    union { unsigned short s[8]; u32x4 v; } r0, r1;
                    r0.s[0] = f2bf(w0.x); r0.s[1] = f2bf(w0.y); r0.s[2] = f2bf(w0.z); r0.s[3] = f2bf(w0.w);
                    r0.s[4] = f2bf(w1.x); r0.s[5] = f2bf(w1.y); r0.s[6] = f2bf(w1.z); r0.s[7] = f2bf(w1.w);
                    r1.s[0] = f2bf(w2.x); r1.s[1] = f2bf(w2.y); r1.s[2] = f2bf(w2.z); r1.s[3] = f2bf(w2.w);
                    r1.s[4] = f2bf(w3.x); r1.s[5] = f2bf(w3.y); r1.s[6] = f2bf(w3.z); r1.s[7] = f2bf(w3.w);
                    __syncthreads();
                    *(u32x4*)&A1[rA][ch] = av0;
                    *(u32x4*)&A1[rA][ch + 8] = av1;
                    *(u32x4*)&W1[rA][ch] = r0.v;
                    *(u32x4*)&W1[rA][ch + 8] = r1.v;
                    __syncthreads();
                    bf16x8 af[4], bf[4];
                    #pragma unroll
                    for (int a2 = 0; a2 < 4; ++a2) af[a2] = *(const bf16x8*)&A1[mw2 + a2 * 16 + fl][fk];
                    #pragma unroll
                    for (int b2 = 0; b2 < 4; ++b2) bf[b2] = *(const bf16x8*)&W1[nw2 + b2 * 16 + fl][fk];
                    #pragma unroll
                    for (int a2 = 0; a2 < 4; ++a2)
                        #pragma unroll
                        for (int b2 = 0; b2 < 4; ++b2)
                            acc[a2][b2] = MFMA16(af[a2], bf[b2], acc[a2][b2]);
                }

                #pragma unroll
                for (int a2 = 0; a2 < 4; ++a2)
                    #pragma unroll
                    for (int b2 = 0; b2 < 4; ++b2) {
                        int col = n0j + nw2 + b2 * 16 + fl;
                        float bv = gbias[col];
                        #pragma unroll
                        for (int j = 0; j < 4; ++j) {
                            int rloc = mw2 + a2 * 16 + (l >> 4) * 4 + j;
                            int m = mt2 * 2 + (rloc >> 6), tl = rloc & 63;
                            gout[((size_t)m * TC_ + tl) * G_ + col] = f2bf(acc[a2][b2][j] + bv);
                        }
                    }
            }
        }
        return;
    }

    // ---- scan blocks ----
    const int dir = bid >> 5;
    const int rb  = bid & 31;
    const int ug  = rb >> 2;               // unit-group [0,8)
    const int bg  = rb & 3;                // batch-group [0,4)
    const int w = tid >> 6, l = tid & 63;
    const int fl = l & 15, q = l >> 4, fko = q * 8;
    const unsigned short* xp = dir ? xpc_b : xpc_f;
    const unsigned short* whh = dir ? whh_b : whh_f;   // bf16
    const float* bhh = dir ? bhh_b : bhh_f;
    unsigned short* outp = dir ? out_b : out_f;
    int* pollb  = flags + (dir * 4 + bg) * 32 * 32;  // 32 wave-flags, 128B apart
    int* myflag = pollb + (ug * 4 + w) * 32;

    // W_hh (bf16) -> VGPR fragments, once per chunk
    const int u0w = ug * 64 + w * 16;
    bf16x8 wv[3][16];
    #pragma unroll
    for (int g = 0; g < 3; ++g)
        #pragma unroll
        for (int ks = 0; ks < 16; ++ks)
            wv[g][ks] = *(const bf16x8*)(whh + (size_t)(g * H_ + u0w + fl) * H_ + ks * 32 + fko);

    const int u = u0w + fl;
    const float br_ = bhh[u], bz_ = bhh[H_ + u], bn_ = bhh[2 * H_ + u];
    const int mb = bg * 16 + q * 4;        // epilogue batch base (4 rows)
    const int srowl = tid >> 4;            // stage: local row [0,16)
    const int sseg  = tid & 15;            // stage: 64B segment

    float hp[4];
    if (c > 0) {
        #pragma unroll
        for (int j = 0; j < 4; ++j) hp[j] = hcar[dir * (B_ * H_) + (mb + j) * H_ + u];
    } else {
        #pragma unroll
        for (int j = 0; j < 4; ++j) hp[j] = 0.f;
    }

    unsigned short xg[3][4];
    auto ldxp = [&](int tl) {
        #pragma unroll
        for (int j = 0; j < 4; ++j) {
            const unsigned short* xb = xp + ((size_t)((mb + j) * TC_ + tl) * G_) + u;
            xg[0][j] = xb[0]; xg[1][j] = xb[H_]; xg[2][j] = xb[2 * H_];
        }
    };
    ldxp(dir ? (TC_ - 1) : 0);

    for (int sl = 0; sl < TC_; ++sl) {
        const int s  = c * TC_ + sl;
        const int gs = layer * T_ + s;
        const int t = dir ? (T_ - 1 - s) : s;
        const int tloc = dir ? (TC_ - 1 - sl) : sl;

        f32x4 z4 = { 0.f, 0.f, 0.f, 0.f };
        f32x4 acc[3];
        acc[0] = z4; acc[1] = z4; acc[2] = z4;

        if (s > 0) {
            const unsigned int rpar = (unsigned int)(((s - 1) & 1) * 16384);
            if (sl > 0) {                  // chunk start: prev launch done via stream order
                int v = gs;
                if (l < 32) v = __hip_atomic_load(pollb + l * 32, __ATOMIC_RELAXED, __HIP_MEMORY_SCOPE_AGENT);
                while (!__all(v >= gs)) {
                    __builtin_amdgcn_s_sleep(1);
                    if (l < 32) v = __hip_atomic_load(pollb + l * 32, __ATOMIC_RELAXED, __HIP_MEMORY_SCOPE_AGENT);
                }
                asm volatile("" ::: "memory");   // no hoist of h loads above poll
            }
            // cooperative stage: h(s-1)[bg*16 .. +15][all 512] -> parity LDS (swizzled)
            {
                const ull* src = (const ull*)(hpub
                    + ((size_t)((((s - 1) & 1) * 2 + dir) * B_ + bg * 16 + srowl)) * 256)
                    + sseg * 8;
                ull qv[8];
                #pragma unroll
                for (int i = 0; i < 8; ++i)
                    qv[i] = __hip_atomic_load(src + i, __ATOMIC_RELAXED, __HIP_MEMORY_SCOPE_AGENT);
                char* dst = smem + rpar + srowl * 1024;
                #pragma unroll
                for (int i = 0; i < 4; ++i) {
                    unsigned int byt = (unsigned int)(sseg * 64 + i * 16);
                    byt ^= ((unsigned int)(srowl & 7)) << 4;
                    union { ull qq[2]; u32x4 v4; } pk;
                    pk.qq[0] = qv[2 * i]; pk.qq[1] = qv[2 * i + 1];
                    *(u32x4*)(dst + byt) = pk.v4;
                }
            }
            __syncthreads();               // the single per-step barrier (stage -> read)
            #pragma unroll
            for (int ks = 0; ks < 16; ++ks) {
                unsigned int byt = (unsigned int)(ks * 64 + q * 16);
                byt ^= ((unsigned int)(fl & 7)) << 4;
                bf16x8 afr = *(const bf16x8*)(smem + rpar + fl * 1024 + byt);
                acc[0] = MFMA16(afr, wv[0][ks], acc[0]);
                acc[1] = MFMA16(afr, wv[1][ks], acc[1]);
                acc[2] = MFMA16(afr, wv[2][ks], acc[2]);
            }
        }

        unsigned short hb16s[4];
        #pragma unroll
        for (int j = 0; j < 4; ++j) {
            float xr = bf2f(xg[0][j]);
            float xz = bf2f(xg[1][j]);
            float xn = bf2f(xg[2][j]);
            float r = sigm(xr + acc[0][j] + br_);
            float z = sigm(xz + acc[1][j] + bz_);
            float nn = tanh_(xn + r * (acc[2][j] + bn_));
            float hv = (1.f - z) * nn + z * hp[j];
            hp[j] = hv;
            hb16s[j] = f2bf(hv);
        }

        // packed h stores (even-fl lanes) FIRST ...
        unsigned int* hw = hpub + (size_t)((s & 1) * 2 + dir) * (B_ * 256);
        #pragma unroll
        for (int j = 0; j < 4; ++j) {
            unsigned int pv = (unsigned int)(unsigned short)__shfl_xor((int)hb16s[j], 1);
            if ((fl & 1) == 0) {
                unsigned int pk32 = (unsigned int)hb16s[j] | (pv << 16);
                __hip_atomic_store(hw + (size_t)(mb + j) * 256 + (u >> 1), pk32,
                                   __ATOMIC_RELAXED, __HIP_MEMORY_SCOPE_AGENT);
            }
        }
        asm volatile("" ::: "memory");     // pin issue order: h stores before the below
        // ... then outp stores + next-xp prefetch issue UNDER the h-store ack RT
        #pragma unroll
        for (int j = 0; j < 4; ++j) {
            size_t row = mode ? (size_t)((mb + j) * TC_ + tloc) : ((size_t)(mb + j) * T_ + t);
            outp[row * ldo + u] = hb16s[j];
        }
        if (sl < TC_ - 1) ldxp(dir ? (TC_ - 2 - sl) : (sl + 1));
        // counted wait: <=16 outstanding => the 4 older h stores are acked
        asm volatile("s_waitcnt vmcnt(16)" ::: "memory");
        if (l == 0)                        // per-WAVE flag: own 16-unit slice done
            __hip_atomic_store(myflag, gs + 1, __ATOMIC_RELAXED, __HIP_MEMORY_SCOPE_AGENT);
    }

    #pragma unroll
    for (int j = 0; j < 4; ++j) hcar[dir * (B_ * H_) + (mb + j) * H_ + u] = hp[j];
}

// ---------------- CRF: one block (one wave) per batch element ----------------
__global__ __launch_bounds__(64) void crf_kernel(const float* __restrict__ em,     // [BT][K]
                                                 const int* __restrict__ labels,
                                                 const float* __restrict__ start,
                                                 const float* __restrict__ endv,
                                                 const float* __restrict__ trans,
                                                 float* __restrict__ partials) {
    __shared__ float tr[32 * 32];
    const int b = blockIdx.x, l = threadIdx.x;
    for (int e2 = l; e2 < 961; e2 += 64) {
        int r = e2 / 31, cc = e2 - r * 31;
        tr[r * 32 + cc] = trans[e2];
    }
    if (l < 32) tr[31 * 32 + l] = 0.f;
    __syncthreads();
    const int* lab = labels + b * T_;
    const float* eb = em + (size_t)b * T_ * K_;

    float part = 0.f, cnt = 0.f;
    for (int t = l; t < T_; t += 64) {
        int lt = lab[t];
        if (lt > -1) {
            cnt += 1.f;
            if (t > 0) part += tr[lab[t - 1] * 32 + lt] + eb[t * K_ + lt];
        }
    }
    #pragma unroll
    for (int o = 32; o; o >>= 1) { part += __shfl_xor(part, o); cnt += __shfl_xor(cnt, o); }
    int lastidx = (int)cnt - 1;
    float num = part + start[lab[0]] + eb[lab[0]] + endv[lab[lastidx]];

    const int jj = l & 31, half = l >> 5;
    const int i0 = half * 16;
    const int ecol = (jj < K_) ? jj : (K_ - 1);
    float a = (jj < K_) ? (start[jj] + eb[jj]) : -3.0e38f;
    for (int t = 1; t < T_; ++t) {
        float tv[16];
        float m = -3.0e38f;
        #pragma unroll
        for (int k = 0; k < 16; ++k) {
            float av = __shfl(a, i0 + k);
            float x = av + tr[(i0 + k) * 32 + jj];
            tv[k] = x;
            m = fmaxf(m, x);
        }
        float ss = 0.f;
        #pragma unroll
        for (int k = 0; k < 16; ++k) ss += __expf(tv[k] - m);
        float m2 = __shfl_xor(m, 32), s2 = __shfl_xor(ss, 32);
        float M = fmaxf(m, m2);
        float S = ss * __expf(m - M) + s2 * __expf(m2 - M);
        float anew = eb[t * K_ + ecol] + M + __logf(S);
        a = ((lab[t] > -1) && (jj < K_)) ? anew : a;
    }
    float v = (jj < K_) ? (a + endv[jj]) : -3.0e38f;
    float m = v;
    #pragma unroll
    for (int o = 32; o; o >>= 1) m = fmaxf(m, __shfl_xor(m, o));
    float ss = (half == 0 && jj < K_) ? __expf(v - m) : 0.f;
    #pragma unroll
    for (int o = 32; o; o >>= 1) ss += __shfl_xor(ss, o);
    if (l == 0) partials[b] = num - (m + __logf(ss));
}

__global__ __launch_bounds__(64) void loss_reduce(const float* __restrict__ partials,
                                                  float* __restrict__ out) {
    float v = partials[threadIdx.x];
    #pragma unroll
    for (int o = 32; o; o >>= 1) v += __shfl_xor(v, o);
    if (threadIdx.x == 0) out[0] = -v;
}

__global__ void sentinel(float* __restrict__ out, float v) { out[0] = -v; }

// ---------------- host ----------------
extern "C" void kernel_launch(void* const* d_in, const int* in_sizes, int n_in,
                              void* d_out, int out_size, void* d_ws, size_t ws_size,
                              hipStream_t stream) {
    const int*   ids      = (const int*)d_in[0];
    const int*   labels   = (const int*)d_in[1];
    const float* emb      = (const float*)d_in[2];
    const float* wih[4]   = { (const float*)d_in[3], (const float*)d_in[7], (const float*)d_in[11], (const float*)d_in[15] };
    const float* whh[4]   = { (const float*)d_in[4], (const float*)d_in[8], (const float*)d_in[12], (const float*)d_in[16] };
    const float* bih[4]   = { (const float*)d_in[5], (const float*)d_in[9], (const float*)d_in[13], (const float*)d_in[17] };
    const float* bhh[4]   = { (const float*)d_in[6], (const float*)d_in[10], (const float*)d_in[14], (const float*)d_in[18] };
    const float* cls_w    = (const float*)d_in[19];
    const float* cls_b    = (const float*)d_in[20];
    const float* c_start  = (const float*)d_in[21];
    const float* c_end    = (const float*)d_in[22];
    const float* c_trans  = (const float*)d_in[23];
    float* out = (float*)d_out;
    float* out1 = out + 1;

    char* p = (char*)d_ws;
    size_t used = 0;
    auto alloc = [&](size_t bytes) -> char* {
        char* r = p;
        size_t a = (bytes + 255) & ~(size_t)255;
        p += a; used += a;
        return r;
    };
    unsigned short* xpF[2]; unsigned short* xpB[2];
    for (int i = 0; i < 2; ++i) {
        xpF[i] = (unsigned short*)alloc((size_t)B_ * TC_ * G_ * 2);   // 12.6MB each
        xpB[i] = (unsigned short*)alloc((size_t)B_ * TC_ * G_ * 2);
    }
    unsigned short* h1   = (unsigned short*)alloc((size_t)BT_ * H2_ * 2);       // 67MB
    unsigned short* gof  = (unsigned short*)alloc((size_t)B_ * TC_ * H_ * 2);   // 4.2MB
    unsigned short* gob  = (unsigned short*)alloc((size_t)B_ * TC_ * H_ * 2);
    unsigned short* clsf  = (unsigned short*)alloc((size_t)32 * H_ * 2);
    unsigned short* clshb = (unsigned short*)alloc((size_t)32 * H_ * 2);
    unsigned short* whhbf = (unsigned short*)alloc((size_t)G_ * H_ * 2);        // per-layer, re-cvt
    unsigned short* whhbb = (unsigned short*)alloc((size_t)G_ * H_ * 2);
    unsigned int*   hpub  = (unsigned int*)alloc((size_t)2 * 2 * B_ * 256 * 4); // 512KB
    float*          hcar  = (float*)alloc((size_t)2 * B_ * H_ * 4);             // 256KB
    float*          partials = (float*)alloc((size_t)B_ * 4);
    int*            flags = (int*)alloc((size_t)2 * 4 * 32 * 32 * 4);           // 32KB

    if (used > ws_size) {
        sentinel<<<dim3(1), dim3(1), 0, stream>>>(out, (float)(ws_size >> 20));
        return;
    }

    hipMemsetAsync(flags, 0, (size_t)2 * 4 * 32 * 32 * 4, stream);
    cvt_cls<<<dim3((32 * H_ + 255) / 256), dim3(256), 0, stream>>>(cls_w, clsf, clshb);
    emis_bias_init<<<dim3(1024), dim3(256), 0, stream>>>(cls_b, out1);

    for (int layer = 0; layer < 2; ++layer) {
        const float* wf  = wih[layer * 2 + 0];
        const float* wb  = wih[layer * 2 + 1];
        const float* bf_ = bih[layer * 2 + 0];
        const float* bb_ = bih[layer * 2 + 1];
        const float* bhf = bhh[layer * 2 + 0];
        const float* bhb = bhh[layer * 2 + 1];

        // convert this layer's W_hh pair -> bf16 (stream-ordered, deterministic)
        cvt_f32_bf16<<<dim3(2048), dim3(256), 0, stream>>>(whh[layer * 2 + 0], whhbf, G_ * H_);
        cvt_f32_bf16<<<dim3(2048), dim3(256), 0, stream>>>(whh[layer * 2 + 1], whhbb, G_ * H_);

        // chunk-0 xp GEMMs (standalone, full grid)
        if (layer == 0) {
            gemm_k<false, false, true, true><<<dim3(64, 24), dim3(256), 0, stream>>>(
                nullptr, emb, ids, E_, 0, T_, wf, E_, G_, bf_, (void*)xpF[0], G_, 0, TC_, G_, E_);
            gemm_k<false, false, true, true><<<dim3(64, 24), dim3(256), 0, stream>>>(
                nullptr, emb, ids, E_, T_ - TC_, T_, wb, E_, G_, bb_, (void*)xpB[0], G_, 0, TC_, G_, E_);
        } else {
            gemm_k<false, false, true, false><<<dim3(64, 24), dim3(256), 0, stream>>>(
                h1, nullptr, nullptr, H2_, 0, T_, wf, H2_, G_, bf_, (void*)xpF[0], G_, 0, TC_, G_, H2_);
            gemm_k<false, false, true, false><<<dim3(64, 24), dim3(256), 0, stream>>>(
                h1, nullptr, nullptr, H2_, T_ - TC_, T_, wb, H2_, G_, bb_, (void*)xpB[0], G_, 0, TC_, G_, H2_);
        }

        for (int c = 0; c < NC_; ++c) {
            int dg = (c + 1 < NC_) ? 1 : 0;
            int t0f_n = (c + 1) * TC_;
            int t0b_n = T_ - (c + 2) * TC_;
            if (layer == 0) {
                fused_scan_gemm<true><<<dim3(256), dim3(256), 0, stream>>>(
                    c, 0, xpF[c & 1], xpB[c & 1], whhbf, whhbb, bhf, bhb, hpub, hcar,
                    h1, h1 + H_, H2_, 0, flags,
                    nullptr, emb, ids, E_, wf, wb, bf_, bb_,
                    xpF[(c + 1) & 1], xpB[(c + 1) & 1], t0f_n, t0b_n, dg);
            } else {
                fused_scan_gemm<false><<<dim3(256), dim3(256), 0, stream>>>(
                    c, 1, xpF[c & 1], xpB[c & 1], whhbf, whhbb, bhf, bhb, hpub, hcar,
                    gof, gob, H_, 1, flags,
                    h1, nullptr, nullptr, H2_, wf, wb, bf_, bb_,
                    xpF[(c + 1) & 1], xpB[(c + 1) & 1], t0f_n, t0b_n, dg);
                // emissions for this chunk (merged pair, += into out1)
                int t0f = c * TC_;
                int t0b = T_ - (c + 1) * TC_;
                emis_k<<<dim3(64, 2), dim3(256), 0, stream>>>(gof, gob, clsf, clshb, out1, t0f, t0b);
            }
        }
    }

    crf_kernel<<<dim3(B_), dim3(64), 0, stream>>>(out1, labels, c_start, c_end, c_trans, partials);
    loss_reduce<<<dim3(1), dim3(64), 0, stream>>>(partials, out);
}

// Round 13
// 4283.183 us; speedup vs baseline: 6.8728x; 1.0039x over previous
//
#include <hip/hip_runtime.h>

#define DI __device__ __forceinline__

constexpr int B_  = 64;
constexpr int T_  = 512;
constexpr int E_  = 256;
constexpr int H_  = 512;
constexpr int G_  = 1536;   // 3*H
constexpr int H2_ = 1024;   // 2*H
constexpr int K_  = 31;
constexpr int BT_ = B_ * T_;
constexpr int TC_ = 64;     // time-chunk length
constexpr int NC_ = T_ / TC_;

typedef float        f32x4  __attribute__((ext_vector_type(4)));
typedef short        bf16x8 __attribute__((ext_vector_type(8)));
typedef unsigned int u32x4  __attribute__((ext_vector_type(4)));
typedef unsigned long long ull;

DI float bf2f(unsigned short u) {
    union { unsigned int i; float f; } v; v.i = ((unsigned int)u) << 16; return v.f;
}
DI unsigned short f2bf(float f) {
    union { float f; unsigned int i; } v; v.f = f;
    unsigned int r = v.i + 0x7fffu + ((v.i >> 16) & 1u);
    return (unsigned short)(r >> 16);
}
DI float sigm(float x) { return 1.f / (1.f + __expf(-x)); }
DI float tanh_(float x) {
    x = fminf(15.f, fmaxf(-15.f, x));
    float e = __expf(-2.f * x);
    return (1.f - e) / (1.f + e);
}

#define MFMA16(a, b, c) __builtin_amdgcn_mfma_f32_16x16x32_bf16(a, b, c, 0, 0, 0)

// ---------------- fp32 -> bf16 convert ----------------
__global__ void cvt_f32_bf16(const float* __restrict__ src, unsigned short* __restrict__ dst, int n) {
    int i = blockIdx.x * blockDim.x + threadIdx.x;
    int stride = gridDim.x * blockDim.x;
    for (; i < n; i += stride) dst[i] = f2bf(src[i]);
}

// classifier weight split halves -> bf16, pad rows 31.. with zeros
__global__ __launch_bounds__(256) void cvt_cls(const float* __restrict__ src,
                                               unsigned short* __restrict__ dstf,
                                               unsigned short* __restrict__ dstb) {
    int i = blockIdx.x * 256 + threadIdx.x;          // [0, 32*512)
    if (i >= 32 * H_) return;
    int n = i >> 9, k = i & 511;
    float vf = (n < K_) ? src[n * H2_ + k] : 0.f;
    float vb = (n < K_) ? src[n * H2_ + H_ + k] : 0.f;
    dstf[i] = f2bf(vf);
    dstb[i] = f2bf(vb);
}

// emissions bias pre-fill (makes later += replay-deterministic)
__global__ __launch_bounds__(256) void emis_bias_init(const float* __restrict__ cls_b,
                                                      float* __restrict__ out1) {
    int i = blockIdx.x * 256 + threadIdx.x;
    int stride = gridDim.x * 256;
    for (; i < BT_ * K_; i += stride) {
        int n = i - (i / K_) * K_;
        out1[i] = cls_b[n];
    }
}

// ---------------- shared GEMM tile body (256 threads, 64x64, bf16 W) ----------------
template <bool OUTF32, bool ACCUM, bool AGATHER>
DI void gemm_tile(unsigned short (*As)[40], unsigned short (*Ws)[40],
                  const unsigned short* A, const float* gsrc, const int* ids, int lda,
                  size_t arow0, const unsigned short* W, int ldw, int nrows, int n0,
                  const float* bias, void* Cout, int ldc, size_t crow0,
                  int nout, int ksz, int tid) {
    const int w = tid >> 6, l = tid & 63;
    const int srow = tid >> 2, sc8 = (tid & 3) * 8;
    const int mw = (w >> 1) * 32, nw = (w & 1) * 32;
    const int fl = l & 15, fk = (l >> 4) * 8;
    f32x4 z4 = { 0.f, 0.f, 0.f, 0.f };
    f32x4 acc[2][2];
    acc[0][0] = z4; acc[0][1] = z4; acc[1][0] = z4; acc[1][1] = z4;
    size_t abase;
    if (AGATHER) abase = (size_t)ids[arow0 + srow] * lda;
    else         abase = (arow0 + srow) * (size_t)lda;

    for (int kc = 0; kc < ksz; kc += 32) {
        u32x4 av, wvv;
        if (AGATHER) {
            const float4* ap = (const float4*)(gsrc + abase + kc + sc8);
            float4 a0 = ap[0], a1 = ap[1];
            union { unsigned short s[8]; u32x4 v; } r;
            r.s[0] = f2bf(a0.x); r.s[1] = f2bf(a0.y); r.s[2] = f2bf(a0.z); r.s[3] = f2bf(a0.w);
            r.s[4] = f2bf(a1.x); r.s[5] = f2bf(a1.y); r.s[6] = f2bf(a1.z); r.s[7] = f2bf(a1.w);
            av = r.v;
        } else {
            av = *(const u32x4*)(A + abase + kc + sc8);
        }
        if (n0 + srow < nrows)
            wvv = *(const u32x4*)(W + (size_t)(n0 + srow) * ldw + kc + sc8);
        else { u32x4 zz = { 0u, 0u, 0u, 0u }; wvv = zz; }
        __syncthreads();
        *(u32x4*)&As[srow][sc8] = av;
        *(u32x4*)&Ws[srow][sc8] = wvv;
        __syncthreads();
        bf16x8 a0 = *(const bf16x8*)&As[mw + fl][fk];
        bf16x8 a1 = *(const bf16x8*)&As[mw + 16 + fl][fk];
        bf16x8 b0 = *(const bf16x8*)&Ws[nw + fl][fk];
        bf16x8 b1 = *(const bf16x8*)&Ws[nw + 16 + fl][fk];
        acc[0][0] = MFMA16(a0, b0, acc[0][0]);
        acc[0][1] = MFMA16(a0, b1, acc[0][1]);
        acc[1][0] = MFMA16(a1, b0, acc[1][0]);
        acc[1][1] = MFMA16(a1, b1, acc[1][1]);
    }

    #pragma unroll
    for (int mf = 0; mf < 2; ++mf)
        #pragma unroll
        for (int nf = 0; nf < 2; ++nf) {
            int col = n0 + nw + nf * 16 + fl;
            if (col >= nout) continue;
            float bv = bias ? bias[col] : 0.f;
            #pragma unroll
            for (int j = 0; j < 4; ++j) {
                int r = mw + mf * 16 + (l >> 4) * 4 + j;
                size_t crow = crow0 + r;
                float v = acc[mf][nf][j] + bv;
                if (OUTF32) {
                    float* C = (float*)Cout;
                    if (ACCUM) C[crow * ldc + col] += v;
                    else       C[crow * ldc + col] = v;
                } else {
                    ((unsigned short*)Cout)[crow * ldc + col] = f2bf(v);
                }
            }
        }
}

template <bool OUTF32, bool ACCUM, bool AGATHER>
__global__ __launch_bounds__(256) void gemm_k(
        const unsigned short* __restrict__ A, const float* __restrict__ gsrc,
        const int* __restrict__ ids, int lda, int m_base, int astride,
        const unsigned short* __restrict__ W, int ldw, int nrows,
        const float* __restrict__ bias,
        void* __restrict__ Cout, int ldc, int c_base, int cstride, int nout, int ksz) {
    __shared__ unsigned short As[64][40];
    __shared__ unsigned short Ws[64][40];
    gemm_tile<OUTF32, ACCUM, AGATHER>(As, Ws, A, gsrc, ids, lda,
        (size_t)m_base + (size_t)blockIdx.x * astride, W, ldw, nrows,
        blockIdx.y * 64, bias, Cout, ldc,
        (size_t)c_base + (size_t)blockIdx.x * cstride, nout, ksz, threadIdx.x);
}

// merged emissions: grid (64,2); y=0 -> gof half, y=1 -> gob half. += into out1.
__global__ __launch_bounds__(256) void emis_k(
        const unsigned short* __restrict__ gof, const unsigned short* __restrict__ gob,
        const unsigned short* __restrict__ clsf, const unsigned short* __restrict__ clsb,
        float* __restrict__ out1, int t0f, int t0b) {
    __shared__ unsigned short As[64][40];
    __shared__ unsigned short Ws[64][40];
    const unsigned short* A = blockIdx.y ? gob : gof;
    const unsigned short* W = blockIdx.y ? clsb : clsf;
    int t0 = blockIdx.y ? t0b : t0f;
    gemm_tile<true, true, false>(As, Ws, A, nullptr, nullptr, H_,
        (size_t)blockIdx.x * TC_, W, H_, 32, 0, nullptr,
        (void*)out1, K_, (size_t)t0 + (size_t)blockIdx.x * T_, K_, H_, threadIdx.x);
}

// ---------------- fused: persistent GRU scan (blocks 0-63) + next-chunk xp GEMM ----------------
// Scan: r12 structure (per-wave flags, 2-parity LDS, one syncthreads/step,
// counted vmcnt drain). GEMM deltas: bf16 W everywhere (pre-converted);
// layer-1 128x128 tile with L2-friendly phase order job=it*192+gb (all 192
// blocks share 6 W tiles per phase -> W stays L2-resident).
template <bool AGATHER>
__global__ __launch_bounds__(256, 1) void fused_scan_gemm(
        int c, int layer,
        const unsigned short* __restrict__ xpc_f, const unsigned short* __restrict__ xpc_b,
        const unsigned short* __restrict__ whh_f, const unsigned short* __restrict__ whh_b,
        const float* __restrict__ bhh_f, const float* __restrict__ bhh_b,
        unsigned int* __restrict__ hpub,    // [parity][dir][B][256] u32 (2 packed bf16)
        float* __restrict__ hcar,           // [dir][B][H] f32 chunk-carry
        unsigned short* __restrict__ out_f, unsigned short* __restrict__ out_b,
        int ldo, int mode, int* __restrict__ flags,
        const unsigned short* __restrict__ gA, const float* __restrict__ gsrc,
        const int* __restrict__ gids, int glda,
        const unsigned short* __restrict__ gwf, const unsigned short* __restrict__ gwb,
        const float* __restrict__ gbf, const float* __restrict__ gbb,
        unsigned short* __restrict__ xpf_nxt, unsigned short* __restrict__ xpb_nxt,
        int t0f_n, int t0b_n, int do_gemm) {
    __shared__ __align__(16) char smem[32768];
    const int bid = blockIdx.x;
    const int tid = threadIdx.x;

    if (bid >= 64) {                       // ---- GEMM blocks ----
        if (!do_gemm) return;
        const int gb = bid - 64;
        if (AGATHER) {
            // layer-0: 64x64 gather path, bf16 W
            unsigned short (*As)[40] = (unsigned short (*)[40])smem;
            unsigned short (*Ws)[40] = (unsigned short (*)[40])(smem + 5120);
            for (int job = gb; job < 2 * 64 * 24; job += 192) {
                int dirj = job & 1;
                int rest = job >> 1;
                int mt = rest & 63;
                int nt = rest >> 6;
                const unsigned short* gw = dirj ? gwb : gwf;
                const float* gbias = dirj ? gbb : gbf;
                unsigned short* gout = dirj ? xpb_nxt : xpf_nxt;
                int t0 = dirj ? t0b_n : t0f_n;
                gemm_tile<false, false, true>(As, Ws, gA, gsrc, gids, glda,
                    (size_t)t0 + (size_t)mt * T_, gw, glda, G_, nt * 64, gbias,
                    (void*)gout, G_, (size_t)mt * TC_, G_, glda, tid);
            }
        } else {
            // layer-1: 128x128 tile, bf16 W, phase order it*192+gb (L2-friendly)
            unsigned short (*A1)[40] = (unsigned short (*)[40])smem;            // [128][40]
            unsigned short (*W1)[40] = (unsigned short (*)[40])(smem + 10240);  // [128][40]
            const int w = tid >> 6, l = tid & 63;
            const int fl = l & 15, fk = (l >> 4) * 8;
            const int mw2 = (w >> 1) * 64, nw2 = (w & 1) * 64;
            const int rA = tid >> 1, ch = (tid & 1) * 16;   // stage row, col-half
            #pragma unroll 1
            for (int it = 0; it < 4; ++it) {
                int job = it * 192 + gb;       // phase-major: 192 concurrent jobs share 6 W tiles
                int dirj = (job >= 384) ? 1 : 0;
                int jj = job - dirj * 384;
                int nt = jj >> 5;              // [0,12)
                int mt2 = jj & 31;             // [0,32)
                const unsigned short* gw = dirj ? gwb : gwf;
                const float* gbias = dirj ? gbb : gbf;
                unsigned short* gout = dirj ? xpb_nxt : xpf_nxt;
                int t0 = dirj ? t0b_n : t0f_n;
                int n0j = nt * 128;
                const int mA = mt2 * 2 + (rA >> 6), tlA = rA & 63;
                const unsigned short* aRow = gA + ((size_t)mA * T_ + t0 + tlA) * H2_ + ch;
                const unsigned short* wRow = gw + (size_t)(n0j + rA) * H2_ + ch;
                f32x4 z4 = { 0.f, 0.f, 0.f, 0.f };
                f32x4 acc[4][4];
                #pragma unroll
                for (int a2 = 0; a2 < 4; ++a2)
                    #pragma unroll
                    for (int b2 = 0; b2 < 4; ++b2) acc[a2][b2] = z4;

                for (int kc = 0; kc < H2_; kc += 32) {
                    u32x4 av0 = *(const u32x4*)(aRow + kc);
                    u32x4 av1 = *(const u32x4*)(aRow + kc + 8);
                    u32x4 wv0 = *(const u32x4*)(wRow + kc);
                    u32x4 wv1 = *(const u32x4*)(wRow + kc + 8);
                    __syncthreads();
                    *(u32x4*)&A1[rA][ch] = av0;
                    *(u32x4*)&A1[rA][ch + 8] = av1;
                    *(u32x4*)&W1[rA][ch] = wv0;
                    *(u32x4*)&W1[rA][ch + 8] = wv1;
                    __syncthreads();
                    bf16x8 af[4], bf[4];
                    #pragma unroll
                    for (int a2 = 0; a2 < 4; ++a2) af[a2] = *(const bf16x8*)&A1[mw2 + a2 * 16 + fl][fk];
                    #pragma unroll
                    for (int b2 = 0; b2 < 4; ++b2) bf[b2] = *(const bf16x8*)&W1[nw2 + b2 * 16 + fl][fk];
                    #pragma unroll
                    for (int a2 = 0; a2 < 4; ++a2)
                        #pragma unroll
                        for (int b2 = 0; b2 < 4; ++b2)
                            acc[a2][b2] = MFMA16(af[a2], bf[b2], acc[a2][b2]);
                }

                #pragma unroll
                for (int a2 = 0; a2 < 4; ++a2)
                    #pragma unroll
                    for (int b2 = 0; b2 < 4; ++b2) {
                        int col = n0j + nw2 + b2 * 16 + fl;
                        float bv = gbias[col];
                        #pragma unroll
                        for (int j = 0; j < 4; ++j) {
                            int rloc = mw2 + a2 * 16 + (l >> 4) * 4 + j;
                            int m = mt2 * 2 + (rloc >> 6), tl = rloc & 63;
                            gout[((size_t)m * TC_ + tl) * G_ + col] = f2bf(acc[a2][b2][j] + bv);
                        }
                    }
            }
        }
        return;
    }

    // ---- scan blocks ----
    const int dir = bid >> 5;
    const int rb  = bid & 31;
    const int ug  = rb >> 2;               // unit-group [0,8)
    const int bg  = rb & 3;                // batch-group [0,4)
    const int w = tid >> 6, l = tid & 63;
    const int fl = l & 15, q = l >> 4, fko = q * 8;
    const unsigned short* xp = dir ? xpc_b : xpc_f;
    const unsigned short* whh = dir ? whh_b : whh_f;   // bf16
    const float* bhh = dir ? bhh_b : bhh_f;
    unsigned short* outp = dir ? out_b : out_f;
    int* pollb  = flags + (dir * 4 + bg) * 32 * 32;  // 32 wave-flags, 128B apart
    int* myflag = pollb + (ug * 4 + w) * 32;

    // W_hh (bf16) -> VGPR fragments, once per chunk
    const int u0w = ug * 64 + w * 16;
    bf16x8 wv[3][16];
    #pragma unroll
    for (int g = 0; g < 3; ++g)
        #pragma unroll
        for (int ks = 0; ks < 16; ++ks)
            wv[g][ks] = *(const bf16x8*)(whh + (size_t)(g * H_ + u0w + fl) * H_ + ks * 32 + fko);

    const int u = u0w + fl;
    const float br_ = bhh[u], bz_ = bhh[H_ + u], bn_ = bhh[2 * H_ + u];
    const int mb = bg * 16 + q * 4;        // epilogue batch base (4 rows)
    const int srowl = tid >> 4;            // stage: local row [0,16)
    const int sseg  = tid & 15;            // stage: 64B segment

    float hp[4];
    if (c > 0) {
        #pragma unroll
        for (int j = 0; j < 4; ++j) hp[j] = hcar[dir * (B_ * H_) + (mb + j) * H_ + u];
    } else {
        #pragma unroll
        for (int j = 0; j < 4; ++j) hp[j] = 0.f;
    }

    unsigned short xg[3][4];
    auto ldxp = [&](int tl) {
        #pragma unroll
        for (int j = 0; j < 4; ++j) {
            const unsigned short* xb = xp + ((size_t)((mb + j) * TC_ + tl) * G_) + u;
            xg[0][j] = xb[0]; xg[1][j] = xb[H_]; xg[2][j] = xb[2 * H_];
        }
    };
    ldxp(dir ? (TC_ - 1) : 0);

    for (int sl = 0; sl < TC_; ++sl) {
        const int s  = c * TC_ + sl;
        const int gs = layer * T_ + s;
        const int t = dir ? (T_ - 1 - s) : s;
        const int tloc = dir ? (TC_ - 1 - sl) : sl;

        f32x4 z4 = { 0.f, 0.f, 0.f, 0.f };
        f32x4 acc[3];
        acc[0] = z4; acc[1] = z4; acc[2] = z4;

        if (s > 0) {
            const unsigned int rpar = (unsigned int)(((s - 1) & 1) * 16384);
            if (sl > 0) {                  // chunk start: prev launch done via stream order
                int v = gs;
                if (l < 32) v = __hip_atomic_load(pollb + l * 32, __ATOMIC_RELAXED, __HIP_MEMORY_SCOPE_AGENT);
                while (!__all(v >= gs)) {
                    __builtin_amdgcn_s_sleep(1);
                    if (l < 32) v = __hip_atomic_load(pollb + l * 32, __ATOMIC_RELAXED, __HIP_MEMORY_SCOPE_AGENT);
                }
                asm volatile("" ::: "memory");   // no hoist of h loads above poll
            }
            // cooperative stage: h(s-1)[bg*16 .. +15][all 512] -> parity LDS (swizzled)
            {
                const ull* src = (const ull*)(hpub
                    + ((size_t)((((s - 1) & 1) * 2 + dir) * B_ + bg * 16 + srowl)) * 256)
                    + sseg * 8;
                ull qv[8];
                #pragma unroll
                for (int i = 0; i < 8; ++i)
                    qv[i] = __hip_atomic_load(src + i, __ATOMIC_RELAXED, __HIP_MEMORY_SCOPE_AGENT);
                char* dst = smem + rpar + srowl * 1024;
                #pragma unroll
                for (int i = 0; i < 4; ++i) {
                    unsigned int byt = (unsigned int)(sseg * 64 + i * 16);
                    byt ^= ((unsigned int)(srowl & 7)) << 4;
                    union { ull qq[2]; u32x4 v4; } pk;
                    pk.qq[0] = qv[2 * i]; pk.qq[1] = qv[2 * i + 1];
                    *(u32x4*)(dst + byt) = pk.v4;
                }
            }
            __syncthreads();               // the single per-step barrier (stage -> read)
            #pragma unroll
            for (int ks = 0; ks < 16; ++ks) {
                unsigned int byt = (unsigned int)(ks * 64 + q * 16);
                byt ^= ((unsigned int)(fl & 7)) << 4;
                bf16x8 afr = *(const bf16x8*)(smem + rpar + fl * 1024 + byt);
                acc[0] = MFMA16(afr, wv[0][ks], acc[0]);
                acc[1] = MFMA16(afr, wv[1][ks], acc[1]);
                acc[2] = MFMA16(afr, wv[2][ks], acc[2]);
            }
        }

        unsigned short hb16s[4];
        #pragma unroll
        for (int j = 0; j < 4; ++j) {
            float xr = bf2f(xg[0][j]);
            float xz = bf2f(xg[1][j]);
            float xn = bf2f(xg[2][j]);
            float r = sigm(xr + acc[0][j] + br_);
            float z = sigm(xz + acc[1][j] + bz_);
            float nn = tanh_(xn + r * (acc[2][j] + bn_));
            float hv = (1.f - z) * nn + z * hp[j];
            hp[j] = hv;
            hb16s[j] = f2bf(hv);
        }

        // packed h stores (even-fl lanes) FIRST ...
        unsigned int* hw = hpub + (size_t)((s & 1) * 2 + dir) * (B_ * 256);
        #pragma unroll
        for (int j = 0; j < 4; ++j) {
            unsigned int pv = (unsigned int)(unsigned short)__shfl_xor((int)hb16s[j], 1);
            if ((fl & 1) == 0) {
                unsigned int pk32 = (unsigned int)hb16s[j] | (pv << 16);
                __hip_atomic_store(hw + (size_t)(mb + j) * 256 + (u >> 1), pk32,
                                   __ATOMIC_RELAXED, __HIP_MEMORY_SCOPE_AGENT);
            }
        }
        asm volatile("" ::: "memory");     // pin issue order: h stores before the below
        // ... then outp stores + next-xp prefetch issue UNDER the h-store ack RT
        #pragma unroll
        for (int j = 0; j < 4; ++j) {
            size_t row = mode ? (size_t)((mb + j) * TC_ + tloc) : ((size_t)(mb + j) * T_ + t);
            outp[row * ldo + u] = hb16s[j];
        }
        if (sl < TC_ - 1) ldxp(dir ? (TC_ - 2 - sl) : (sl + 1));
        // counted wait: <=16 outstanding => the 4 older h stores are acked
        asm volatile("s_waitcnt vmcnt(16)" ::: "memory");
        if (l == 0)                        // per-WAVE flag: own 16-unit slice done
            __hip_atomic_store(myflag, gs + 1, __ATOMIC_RELAXED, __HIP_MEMORY_SCOPE_AGENT);
    }

    #pragma unroll
    for (int j = 0; j < 4; ++j) hcar[dir * (B_ * H_) + (mb + j) * H_ + u] = hp[j];
}

// ---------------- CRF: one block (one wave) per batch element ----------------
__global__ __launch_bounds__(64) void crf_kernel(const float* __restrict__ em,     // [BT][K]
                                                 const int* __restrict__ labels,
                                                 const float* __restrict__ start,
                                                 const float* __restrict__ endv,
                                                 const float* __restrict__ trans,
                                                 float* __restrict__ partials) {
    __shared__ float tr[32 * 32];
    const int b = blockIdx.x, l = threadIdx.x;
    for (int e2 = l; e2 < 961; e2 += 64) {
        int r = e2 / 31, cc = e2 - r * 31;
        tr[r * 32 + cc] = trans[e2];
    }
    if (l < 32) tr[31 * 32 + l] = 0.f;
    __syncthreads();
    const int* lab = labels + b * T_;
    const float* eb = em + (size_t)b * T_ * K_;

    float part = 0.f, cnt = 0.f;
    for (int t = l; t < T_; t += 64) {
        int lt = lab[t];
        if (lt > -1) {
            cnt += 1.f;
            if (t > 0) part += tr[lab[t - 1] * 32 + lt] + eb[t * K_ + lt];
        }
    }
    #pragma unroll
    for (int o = 32; o; o >>= 1) { part += __shfl_xor(part, o); cnt += __shfl_xor(cnt, o); }
    int lastidx = (int)cnt - 1;
    float num = part + start[lab[0]] + eb[lab[0]] + endv[lab[lastidx]];

    const int jj = l & 31, half = l >> 5;
    const int i0 = half * 16;
    const int ecol = (jj < K_) ? jj : (K_ - 1);
    float a = (jj < K_) ? (start[jj] + eb[jj]) : -3.0e38f;
    for (int t = 1; t < T_; ++t) {
        float tv[16];
        float m = -3.0e38f;
        #pragma unroll
        for (int k = 0; k < 16; ++k) {
            float av = __shfl(a, i0 + k);
            float x = av + tr[(i0 + k) * 32 + jj];
            tv[k] = x;
            m = fmaxf(m, x);
        }
        float ss = 0.f;
        #pragma unroll
        for (int k = 0; k < 16; ++k) ss += __expf(tv[k] - m);
        float m2 = __shfl_xor(m, 32), s2 = __shfl_xor(ss, 32);
        float M = fmaxf(m, m2);
        float S = ss * __expf(m - M) + s2 * __expf(m2 - M);
        float anew = eb[t * K_ + ecol] + M + __logf(S);
        a = ((lab[t] > -1) && (jj < K_)) ? anew : a;
    }
    float v = (jj < K_) ? (a + endv[jj]) : -3.0e38f;
    float m = v;
    #pragma unroll
    for (int o = 32; o; o >>= 1) m = fmaxf(m, __shfl_xor(m, o));
    float ss = (half == 0 && jj < K_) ? __expf(v - m) : 0.f;
    #pragma unroll
    for (int o = 32; o; o >>= 1) ss += __shfl_xor(ss, o);
    if (l == 0) partials[b] = num - (m + __logf(ss));
}

__global__ __launch_bounds__(64) void loss_reduce(const float* __restrict__ partials,
                                                  float* __restrict__ out) {
    float v = partials[threadIdx.x];
    #pragma unroll
    for (int o = 32; o; o >>= 1) v += __shfl_xor(v, o);
    if (threadIdx.x == 0) out[0] = -v;
}

__global__ void sentinel(float* __restrict__ out, float v) { out[0] = -v; }

// ---------------- host ----------------
extern "C" void kernel_launch(void* const* d_in, const int* in_sizes, int n_in,
                              void* d_out, int out_size, void* d_ws, size_t ws_size,
                              hipStream_t stream) {
    const int*   ids      = (const int*)d_in[0];
    const int*   labels   = (const int*)d_in[1];
    const float* emb      = (const float*)d_in[2];
    const float* wih[4]   = { (const float*)d_in[3], (const float*)d_in[7], (const float*)d_in[11], (const float*)d_in[15] };
    const float* whh[4]   = { (const float*)d_in[4], (const float*)d_in[8], (const float*)d_in[12], (const float*)d_in[16] };
    const float* bih[4]   = { (const float*)d_in[5], (const float*)d_in[9], (const float*)d_in[13], (const float*)d_in[17] };
    const float* bhh[4]   = { (const float*)d_in[6], (const float*)d_in[10], (const float*)d_in[14], (const float*)d_in[18] };
    const float* cls_w    = (const float*)d_in[19];
    const float* cls_b    = (const float*)d_in[20];
    const float* c_start  = (const float*)d_in[21];
    const float* c_end    = (const float*)d_in[22];
    const float* c_trans  = (const float*)d_in[23];
    float* out = (float*)d_out;
    float* out1 = out + 1;

    char* p = (char*)d_ws;
    size_t used = 0;
    auto alloc = [&](size_t bytes) -> char* {
        char* r = p;
        size_t a = (bytes + 255) & ~(size_t)255;
        p += a; used += a;
        return r;
    };
    unsigned short* xpF[2]; unsigned short* xpB[2];
    for (int i = 0; i < 2; ++i) {
        xpF[i] = (unsigned short*)alloc((size_t)B_ * TC_ * G_ * 2);   // 12.6MB each
        xpB[i] = (unsigned short*)alloc((size_t)B_ * TC_ * G_ * 2);
    }
    unsigned short* h1   = (unsigned short*)alloc((size_t)BT_ * H2_ * 2);       // 67MB
    unsigned short* gof  = (unsigned short*)alloc((size_t)B_ * TC_ * H_ * 2);   // 4.2MB
    unsigned short* gob  = (unsigned short*)alloc((size_t)B_ * TC_ * H_ * 2);
    unsigned short* clsf  = (unsigned short*)alloc((size_t)32 * H_ * 2);
    unsigned short* clshb = (unsigned short*)alloc((size_t)32 * H_ * 2);
    unsigned short* whhbf = (unsigned short*)alloc((size_t)G_ * H_ * 2);        // per-layer, re-cvt
    unsigned short* whhbb = (unsigned short*)alloc((size_t)G_ * H_ * 2);
    unsigned short* wihbf = (unsigned short*)alloc((size_t)G_ * H2_ * 2);       // 3.1MB, per-layer
    unsigned short* wihbb = (unsigned short*)alloc((size_t)G_ * H2_ * 2);
    unsigned int*   hpub  = (unsigned int*)alloc((size_t)2 * 2 * B_ * 256 * 4); // 512KB
    float*          hcar  = (float*)alloc((size_t)2 * B_ * H_ * 4);             // 256KB
    float*          partials = (float*)alloc((size_t)B_ * 4);
    int*            flags = (int*)alloc((size_t)2 * 4 * 32 * 32 * 4);           // 32KB

    if (used > ws_size) {
        sentinel<<<dim3(1), dim3(1), 0, stream>>>(out, (float)(ws_size >> 20));
        return;
    }

    hipMemsetAsync(flags, 0, (size_t)2 * 4 * 32 * 32 * 4, stream);
    cvt_cls<<<dim3((32 * H_ + 255) / 256), dim3(256), 0, stream>>>(cls_w, clsf, clshb);
    emis_bias_init<<<dim3(1024), dim3(256), 0, stream>>>(cls_b, out1);

    for (int layer = 0; layer < 2; ++layer) {
        const float* bf_ = bih[layer * 2 + 0];
        const float* bb_ = bih[layer * 2 + 1];
        const float* bhf = bhh[layer * 2 + 0];
        const float* bhb = bhh[layer * 2 + 1];
        const int lda = layer ? H2_ : E_;

        // convert this layer's weights -> bf16 (stream-ordered, deterministic)
        cvt_f32_bf16<<<dim3(2048), dim3(256), 0, stream>>>(whh[layer * 2 + 0], whhbf, G_ * H_);
        cvt_f32_bf16<<<dim3(2048), dim3(256), 0, stream>>>(whh[layer * 2 + 1], whhbb, G_ * H_);
        cvt_f32_bf16<<<dim3(2048), dim3(256), 0, stream>>>(wih[layer * 2 + 0], wihbf, G_ * lda);
        cvt_f32_bf16<<<dim3(2048), dim3(256), 0, stream>>>(wih[layer * 2 + 1], wihbb, G_ * lda);

        // chunk-0 xp GEMMs (standalone, full grid, bf16 W)
        if (layer == 0) {
            gemm_k<false, false, true><<<dim3(64, 24), dim3(256), 0, stream>>>(
                nullptr, emb, ids, E_, 0, T_, wihbf, E_, G_, bf_, (void*)xpF[0], G_, 0, TC_, G_, E_);
            gemm_k<false, false, true><<<dim3(64, 24), dim3(256), 0, stream>>>(
                nullptr, emb, ids, E_, T_ - TC_, T_, wihbb, E_, G_, bb_, (void*)xpB[0], G_, 0, TC_, G_, E_);
        } else {
            gemm_k<false, false, false><<<dim3(64, 24), dim3(256), 0, stream>>>(
                h1, nullptr, nullptr, H2_, 0, T_, wihbf, H2_, G_, bf_, (void*)xpF[0], G_, 0, TC_, G_, H2_);
            gemm_k<false, false, false><<<dim3(64, 24), dim3(256), 0, stream>>>(
                h1, nullptr, nullptr, H2_, T_ - TC_, T_, wihbb, H2_, G_, bb_, (void*)xpB[0], G_, 0, TC_, G_, H2_);
        }

        for (int c = 0; c < NC_; ++c) {
            int dg = (c + 1 < NC_) ? 1 : 0;
            int t0f_n = (c + 1) * TC_;
            int t0b_n = T_ - (c + 2) * TC_;
            if (layer == 0) {
                fused_scan_gemm<true><<<dim3(256), dim3(256), 0, stream>>>(
                    c, 0, xpF[c & 1], xpB[c & 1], whhbf, whhbb, bhf, bhb, hpub, hcar,
                    h1, h1 + H_, H2_, 0, flags,
                    nullptr, emb, ids, E_, wihbf, wihbb, bf_, bb_,
                    xpF[(c + 1) & 1], xpB[(c + 1) & 1], t0f_n, t0b_n, dg);
            } else {
                fused_scan_gemm<false><<<dim3(256), dim3(256), 0, stream>>>(
                    c, 1, xpF[c & 1], xpB[c & 1], whhbf, whhbb, bhf, bhb, hpub, hcar,
                    gof, gob, H_, 1, flags,
                    h1, nullptr, nullptr, H2_, wihbf, wihbb, bf_, bb_,
                    xpF[(c + 1) & 1], xpB[(c + 1) & 1], t0f_n, t0b_n, dg);
                // emissions for this chunk (merged pair, += into out1)
                int t0f = c * TC_;
                int t0b = T_ - (c + 1) * TC_;
                emis_k<<<dim3(64, 2), dim3(256), 0, stream>>>(gof, gob, clsf, clshb, out1, t0f, t0b);
            }
        }
    }

    crf_kernel<<<dim3(B_), dim3(64), 0, stream>>>(out1, labels, c_start, c_end, c_trans, partials);
    loss_reduce<<<dim3(1), dim3(64), 0, stream>>>(partials, out);
}